// Round 10
// baseline (475.717 us; speedup 1.0000x reference)
//
#include <hip/hip_runtime.h>

#define B_     256
#define L_     128
#define D_     6
#define F_     200
#define FA_    39
#define FB_    10
#define PAD_   127       // L-1 padding atom index
#define LMASK  127
#define NT     256
#define KC8    (F_/8)    // 25 short8 chunks per bf16 row
#define NTILE  16        // gather-kernel tile (proven gather geometry)
#define NTILE2 32        // gemm-kernel tile (2 A-frag groups per bfrag)
#define NQ     (NTILE * D_)   // 96 pairs
#define NF     (B_ * L_ * F_) // 6,553,600 floats
#define MSZ    (F_ * F_)      // 40,000 floats per matrix
#define NNODES (B_ * L_)      // 32768
#define NPAIRS (NNODES * D_)  // 196608
#define KP     224            // K padded to 7*32 (MFMA reads k < 224)
#define KPP    232            // LDS row stride: 464B -> bank step 20 (conflict-free)
#define KSTEPS 7
#define NTL    13             // N tiles of 16 (200 -> 208)
#define FRAG_TOTAL (14 * NTL * KSTEPS * 64)
#define PN2    32
#define NPREP  (NNODES / PN2)                     // 1024 prep blocks
#define NBF    ((FRAG_TOTAL + NT - 1) / NT)       // 319 frag blocks

typedef __attribute__((ext_vector_type(8))) short sh8;
typedef __attribute__((ext_vector_type(4))) float f32x4;

__device__ __forceinline__ float lrelu(float x) { return x >= 0.0f ? x : 0.01f * x; }
__device__ __forceinline__ float sigm(float x)  { return 1.0f / (1.0f + __expf(-x)); }
__device__ __forceinline__ float fast_tanh(float x) {   // 1 - 2/(e^2x+1), sat-correct
    const float e = __expf(2.0f * x);
    return 1.0f - 2.0f / (e + 1.0f);
}
__device__ __forceinline__ unsigned short f2b(float x) {   // fp32 -> bf16 RNE
    unsigned int u = __float_as_uint(x);
    unsigned int r = (u + 0x7FFFu + ((u >> 16) & 1u)) >> 16;
    return (unsigned short)r;
}
__device__ __forceinline__ float b2f(unsigned short u) {
    return __uint_as_float(((unsigned int)u) << 16);
}
// A-fragment group g (nodes g*16..g*16+15) from LDS bf16 [NTILE2][KPP]:
// A[m=(lane&15)+16g][k=ks*32+quad*8+j]
#define AFRAG2(arr, ks, g) \
    (*(const sh8*)&arr[(lane & 15) + ((g) << 4)][(ks) * 32 + ((lane >> 4) << 3)])
__device__ __forceinline__ sh8 bfrag(const unsigned short* __restrict__ WFr,
                                     int mat, int t, int ks, int lane) {
    return *(const sh8*)(WFr + ((((size_t)mat * NTL + t) * KSTEPS + ks) * 64 + lane) * 8);
}

// ========== fused: prep (blocks [0,NPREP)) + build_frags (blocks [NPREP,..)) ==========
__global__ __launch_bounds__(NT)
void prep_frags_kernel(const float* __restrict__ atom_list, const float* __restrict__ bond_list,
                       const float* __restrict__ atom_W, const float* __restrict__ atom_b,
                       const float* __restrict__ nbr_W,
                       const float* __restrict__ attend_W,
                       const float* __restrict__ gru_Wih,
                       const float* __restrict__ gru_Whh,
                       float* __restrict__ cur0, unsigned short* __restrict__ cur0b,
                       unsigned short* __restrict__ PA, unsigned short* __restrict__ PB,
                       unsigned short* __restrict__ WF)
{
    __shared__ float wsh[F_ * (FA_ + FB_)];   // 9800 floats = 39.2 KB
    const int tid = threadIdx.x;

    if (blockIdx.x >= NPREP) {
        // ---- build_frags part: bf16 B-fragments, 14 F×F matrices, zero-padded ----
        const int i = (blockIdx.x - NPREP) * NT + tid;
        if (i >= FRAG_TOTAL) return;
        const int lane = i & 63;
        int rest = i >> 6;
        const int ks = rest % KSTEPS; rest /= KSTEPS;
        const int t  = rest % NTL;
        const int m  = rest / NTL;
        const int n  = t * 16 + (lane & 15);
        const int k0 = ks * 32 + ((lane >> 4) << 3);
        const int r = m / 7, tt = m - r * 7;
        const float* src;
        if (tt == 0)      src = attend_W + (size_t)r * MSZ;
        else if (tt <= 3) src = gru_Wih + ((size_t)r * 3 + (tt - 1)) * MSZ;
        else              src = gru_Whh + ((size_t)r * 3 + (tt - 4)) * MSZ;
        unsigned short o[8];
        #pragma unroll
        for (int j = 0; j < 8; ++j) {
            const int k = k0 + j;
            const float v = (n < F_ && k < F_) ? src[(size_t)n * F_ + k] : 0.0f;
            o[j] = f2b(v);
        }
        uint4 w;
        w.x = (unsigned int)o[0] | ((unsigned int)o[1] << 16);
        w.y = (unsigned int)o[2] | ((unsigned int)o[3] << 16);
        w.z = (unsigned int)o[4] | ((unsigned int)o[5] << 16);
        w.w = (unsigned int)o[6] | ((unsigned int)o[7] << 16);
        ((uint4*)WF)[i] = w;
        return;
    }

    // ---- prep part: weight-stationary; lane owns column f, weights in regs ----
    const int node0 = blockIdx.x * PN2;
    const int f     = tid;
    const bool valid = (f < F_);
    const int fc    = valid ? f : 0;

    float wa[FA_];
    float wn[FA_ + FB_];

    for (int i = tid; i < F_ * FA_; i += NT) wsh[i] = atom_W[i];
    __syncthreads();
    #pragma unroll
    for (int k = 0; k < FA_; ++k) wa[k] = wsh[fc * FA_ + k];
    __syncthreads();
    for (int i = tid; i < F_ * (FA_ + FB_); i += NT) wsh[i] = nbr_W[i];
    __syncthreads();
    #pragma unroll
    for (int k = 0; k < FA_ + FB_; ++k) wn[k] = wsh[fc * (FA_ + FB_) + k];

    const float ab = atom_b[fc];

    for (int n = 0; n < PN2; ++n) {
        const float* __restrict__ ar = atom_list + (size_t)(node0 + n) * FA_;
        const float* __restrict__ br = bond_list + (size_t)(node0 + n) * FB_;
        float accA = ab, accPA = 0.0f, accPB = 0.0f;
        #pragma unroll
        for (int k = 0; k < FA_; ++k) {
            const float a = ar[k];          // wave-uniform -> scalar load
            accA  += a * wa[k];
            accPA += a * wn[k];
        }
        #pragma unroll
        for (int k = 0; k < FB_; ++k) accPB += br[k] * wn[FA_ + k];
        if (valid) {
            const size_t o = (size_t)(node0 + n) * F_ + f;
            const float c = lrelu(accA);
            cur0[o]  = c;
            cur0b[o] = f2b(c);
            PA[o]    = f2b(accPA);
            PB[o]    = f2b(accPB);
        }
    }
}

// ===== mode-0 pair-score table: s2p[q] = alW2 · lrelu(PA[nidx]+PB[bidx]+nbr_b) =====
#define PPB 32   // pairs per block, 8 lanes each
__global__ __launch_bounds__(NT)
void pair_score_kernel(const int* __restrict__ atom_degree,
                       const int* __restrict__ bond_degree,
                       const unsigned short* __restrict__ PA,
                       const unsigned short* __restrict__ PB,
                       const float* __restrict__ alW2, const float* __restrict__ nbr_b,
                       float* __restrict__ s2p)
{
    __shared__ float w_s[F_], b_s[F_];
    const int tid = threadIdx.x;
    if (tid < F_) { w_s[tid] = alW2[tid]; b_s[tid] = nbr_b[tid]; }
    // XCD-aligned swizzle: molecule m -> XCD m%8
    const int xcd = blockIdx.x & 7;
    const int j   = blockIdx.x >> 3;            // 0..767
    const int mol = (j / 24) * 8 + xcd;         // 24 blocks per molecule
    const int q0  = mol * (L_ * D_) + (j % 24) * PPB;
    const int q   = q0 + (tid >> 3);
    const int sub = tid & 7;
    const int nidx = atom_degree[q] & LMASK;
    const int bidx = bond_degree[q] & LMASK;
    const int bL   = mol * L_;
    const unsigned short* pa = PA + (size_t)(bL + nidx) * F_;
    const unsigned short* pb = PB + (size_t)(bL + bidx) * F_;
    __syncthreads();
    float s = 0.0f;
    for (int kk = sub; kk < KC8; kk += 8) {
        const sh8 pa8 = *(const sh8*)(pa + kk * 8);
        const sh8 pb8 = *(const sh8*)(pb + kk * 8);
        #pragma unroll
        for (int e = 0; e < 8; ++e)
            s += lrelu(b2f((unsigned short)pa8[e]) + b2f((unsigned short)pb8[e])
                       + b_s[kk * 8 + e]) * w_s[kk * 8 + e];
    }
    s += __shfl_xor(s, 1, 8); s += __shfl_xor(s, 2, 8); s += __shfl_xor(s, 4, 8);
    if (sub == 0) s2p[q] = s;
}

// ============ gather kernel: s1 + scores + softmax + D-mix -> mixed_g, asum_g ============
// Gather-only (no MFMA, no WF stream, ~2.5 KB LDS): launch_bounds(256,8) gives
// up to 8 blocks/CU of TLP to hide the ~200cy L2 gather latency that dominated
// the fused round kernel's A-D phases.
__global__ __launch_bounds__(NT, 8)
void gather_kernel(
    const int*   __restrict__ atom_degree,
    const int*   __restrict__ bond_degree,
    const float* __restrict__ align_W,       // [2F] this round (first half used)
    const float* __restrict__ align_b,       // [1]
    const float* __restrict__ nbr_b,         // mode0
    const unsigned short* __restrict__ PAb,  // mode0, bf16
    const unsigned short* __restrict__ PBb,  // mode0, bf16
    const float* __restrict__ s2_tab,        // mode0: per-pair; mode1: per-node
    const float* __restrict__ cur_in,        // [B,L,F] fp32 (s1)
    const unsigned short* __restrict__ cur_inb, // [B,L,F] bf16 (mode1-D)
    unsigned short* __restrict__ mixed_g,    // out: [NNODES][F_] bf16
    float*       __restrict__ asum_g,        // out: [NNODES] fp32
    int mode)
{
    // XCD swizzle: all 8 tiles of a molecule share (blockIdx % 8) -> same XCD L2
    const int bid   = blockIdx.x;
    const int mol   = ((bid >> 6) << 3) | (bid & 7);
    const int tile  = (bid >> 3) & 7;
    const int node0 = mol * L_ + tile * NTILE;
    const int bL    = mol * L_;
    const int tid   = threadIdx.x;

    __shared__ float nbrb_s[F_];
    __shared__ float sc_s [NQ];
    __shared__ float s1_s[NTILE];
    __shared__ int   nidx_s[NQ];
    __shared__ int   bidx_s[NQ];

    if (tid < NQ) {
        const int n = tid / D_, j = tid - n * D_;
        nidx_s[tid] = atom_degree[(node0 + n) * D_ + j] & LMASK;
        bidx_s[tid] = (mode == 0) ? (bond_degree[(node0 + n) * D_ + j] & LMASK) : 0;
    }
    if (mode == 0 && tid < F_) nbrb_s[tid] = nbr_b[tid];

    // s1[n] = alW1 · cur[n] (16 lanes per node, fp32)
    {
        const int n = tid >> 4, sub = tid & 15;
        const float* crow = cur_in + (size_t)(node0 + n) * F_;
        float a = 0.0f;
        for (int f = sub; f < F_; f += 16) a += crow[f] * align_W[f];
        a += __shfl_xor(a, 1, 16); a += __shfl_xor(a, 2, 16);
        a += __shfl_xor(a, 4, 16); a += __shfl_xor(a, 8, 16);
        if (sub == 0) s1_s[n] = a;
    }
    __syncthreads();

    // scores — table lookup in BOTH modes
    if (tid < NQ) {
        const int n = tid / D_;
        const float s2v = (mode == 0)
            ? s2_tab[(size_t)(node0 + n) * D_ + (tid - n * D_)]
            : s2_tab[bL + nidx_s[tid]];
        float sc = lrelu(s1_s[n] + s2v + align_b[0]);
        if (nidx_s[tid] == PAD_) sc += -9.0e8f;
        sc_s[tid] = sc;
    }
    __syncthreads();

    // masked softmax over D per node; write asum to global
    if (tid < NTILE) {
        float m = sc_s[tid * D_];
        #pragma unroll
        for (int j = 1; j < D_; ++j) m = fmaxf(m, sc_s[tid * D_ + j]);
        float ex[D_]; float ssum = 0.0f;
        #pragma unroll
        for (int j = 0; j < D_; ++j) { ex[j] = __expf(sc_s[tid * D_ + j] - m); ssum += ex[j]; }
        const float inv = 1.0f / ssum;
        float as = 0.0f;
        #pragma unroll
        for (int j = 0; j < D_; ++j) {
            const float a = (nidx_s[tid * D_ + j] == PAD_) ? 0.0f : ex[j] * inv;
            sc_s[tid * D_ + j] = a;
            as += a;
        }
        asum_g[node0 + tid] = as;
    }
    __syncthreads();

    // D: mixed[n] = sum_j attn_j * nbr_feat_j -> GLOBAL bf16 (linear, coalesced)
    for (int idx = tid; idx < NTILE * KC8; idx += NT) {
        const int n = idx / KC8, kk = idx - n * KC8;
        const int c0 = kk * 8;
        float m[8];
        #pragma unroll
        for (int e = 0; e < 8; ++e) m[e] = 0.0f;
        if (mode == 0) {
            #pragma unroll
            for (int j = 0; j < D_; ++j) {
                const float a = sc_s[n * D_ + j];
                const sh8 pa8 = *(const sh8*)(PAb + (size_t)(bL + nidx_s[n*D_+j]) * F_ + c0);
                const sh8 pb8 = *(const sh8*)(PBb + (size_t)(bL + bidx_s[n*D_+j]) * F_ + c0);
                #pragma unroll
                for (int e = 0; e < 8; ++e)
                    m[e] += a * lrelu(b2f((unsigned short)pa8[e])
                                    + b2f((unsigned short)pb8[e]) + nbrb_s[c0 + e]);
            }
        } else {
            #pragma unroll
            for (int j = 0; j < D_; ++j) {
                const float a = sc_s[n * D_ + j];
                const sh8 v8 = *(const sh8*)(cur_inb + (size_t)(bL + nidx_s[n*D_+j]) * F_ + c0);
                #pragma unroll
                for (int e = 0; e < 8; ++e)
                    m[e] += a * b2f((unsigned short)v8[e]);
            }
        }
        uint4 w;
        w.x = (unsigned int)f2b(m[0]) | ((unsigned int)f2b(m[1]) << 16);
        w.y = (unsigned int)f2b(m[2]) | ((unsigned int)f2b(m[3]) << 16);
        w.z = (unsigned int)f2b(m[4]) | ((unsigned int)f2b(m[5]) << 16);
        w.w = (unsigned int)f2b(m[6]) | ((unsigned int)f2b(m[7]) << 16);
        *(uint4*)(mixed_g + (size_t)(node0 + n) * F_ + c0) = w;
    }
}

// ============ gemm kernel: E (ctx) + F (GRU) over 32-node tiles, ZERO gathers ============
// Reads mixed/cur as linear streams (the r4/r9 L2-thrash mechanism cannot occur),
// so NTILE2=32 safely halves the WF B-stream per node (each bfrag feeds 2 A-frags).
// 3 LDS buffers = 44.5 KB -> 3 blocks/CU; bounds(256,3) = 170-VGPR budget.
__global__ __launch_bounds__(NT, 3)
void gemm_kernel(
    const unsigned short* __restrict__ WF,   // 7 fragment matrices this round
    const float* __restrict__ attend_b,
    const float* __restrict__ gru_bih,
    const float* __restrict__ gru_bhh,
    const unsigned short* __restrict__ mixed_g, // [NNODES][F_] bf16
    const float* __restrict__ asum_g,        // [NNODES]
    const float* __restrict__ cur_in,        // [B,L,F] fp32 (epilogue)
    const unsigned short* __restrict__ cur_inb, // [B,L,F] bf16 (A-operand)
    float*       __restrict__ dst,
    unsigned short* __restrict__ dstb,       // bf16 shadow out (mode0 only)
    const float* __restrict__ alW2_next,     // mode0: round-1 alW2 for fused s2
    float*       __restrict__ s2_next,       // mode0: fused s2 output [NNODES]
    int mode)
{
    const int node0 = blockIdx.x * NTILE2;
    const int tid   = threadIdx.x;
    const int lane  = tid & 63;
    const int wave  = tid >> 6;

    __shared__ __align__(16) unsigned short curb  [NTILE2][KPP];
    __shared__ __align__(16) unsigned short mixedb[NTILE2][KPP];
    __shared__ __align__(16) unsigned short ctxb  [NTILE2][KPP];
    __shared__ float asum_s[NTILE2];
    __shared__ float s2acc[NTILE2];

    // zero K-pads [F_, KP)
    for (int idx = tid; idx < NTILE2 * (KP - F_); idx += NT) {
        const int n = idx / (KP - F_), k = F_ + idx % (KP - F_);
        curb[n][k] = 0; mixedb[n][k] = 0; ctxb[n][k] = 0;
    }
    if (tid < NTILE2) { asum_s[tid] = asum_g[node0 + tid]; s2acc[tid] = 0.0f; }

    // stage cur + mixed (pure 16B linear copies)
    for (int idx = tid; idx < NTILE2 * KC8; idx += NT) {
        const int n = idx / KC8, kk = idx - n * KC8;
        *(uint4*)&curb[n][kk * 8] =
            *(const uint4*)(cur_inb + (size_t)(node0 + n) * F_ + kk * 8);
        *(uint4*)&mixedb[n][kk * 8] =
            *(const uint4*)(mixed_g + (size_t)(node0 + n) * F_ + kk * 8);
    }
    __syncthreads();

    // ---- Phase E: ctx = elu(attend_W @ mixed + asum*b), both node groups ----
    for (int t = wave; t < NTL; t += 4) {
        f32x4 a0 = {0.f,0.f,0.f,0.f}, a1 = {0.f,0.f,0.f,0.f};
        #pragma unroll
        for (int ks = 0; ks < KSTEPS; ++ks) {
            const sh8 b = bfrag(WF, 0, t, ks, lane);
            a0 = __builtin_amdgcn_mfma_f32_16x16x32_bf16(AFRAG2(mixedb, ks, 0), b, a0, 0,0,0);
            a1 = __builtin_amdgcn_mfma_f32_16x16x32_bf16(AFRAG2(mixedb, ks, 1), b, a1, 0,0,0);
        }
        const int f = t * 16 + (lane & 15);
        if (f < F_) {
            const float bb = attend_b[f];
            #pragma unroll
            for (int rg = 0; rg < 4; ++rg) {
                const int node = ((lane >> 4) << 2) + rg;
                float c0 = a0[rg] + asum_s[node] * bb;
                c0 = (c0 > 0.0f) ? c0 : (__expf(c0) - 1.0f);
                ctxb[node][f] = f2b(c0);
                float c1 = a1[rg] + asum_s[node + 16] * bb;
                c1 = (c1 > 0.0f) ? c1 : (__expf(c1) - 1.0f);
                ctxb[node + 16][f] = f2b(c1);
            }
        }
    }
    __syncthreads();

    // ---- Phase F: GRU gates, both node groups (+ fused next-round s2) ----
    float s2p0[4] = {0.f,0.f,0.f,0.f}, s2p1[4] = {0.f,0.f,0.f,0.f};
    for (int t = wave; t < NTL; t += 4) {
        f32x4 ar0={0.f,0.f,0.f,0.f}, ar1={0.f,0.f,0.f,0.f};
        f32x4 az0={0.f,0.f,0.f,0.f}, az1={0.f,0.f,0.f,0.f};
        f32x4 ai0={0.f,0.f,0.f,0.f}, ai1={0.f,0.f,0.f,0.f};
        f32x4 ah0={0.f,0.f,0.f,0.f}, ah1={0.f,0.f,0.f,0.f};
        #pragma unroll
        for (int ks = 0; ks < KSTEPS; ++ks) {
            const sh8 b1 = bfrag(WF,1,t,ks,lane), b2 = bfrag(WF,2,t,ks,lane);
            const sh8 b3 = bfrag(WF,3,t,ks,lane), b4 = bfrag(WF,4,t,ks,lane);
            const sh8 b5 = bfrag(WF,5,t,ks,lane), b6 = bfrag(WF,6,t,ks,lane);
            const sh8 ac0 = AFRAG2(ctxb, ks, 0), ac1 = AFRAG2(ctxb, ks, 1);
            const sh8 ah0f = AFRAG2(curb, ks, 0),  ah1f = AFRAG2(curb, ks, 1);
            ar0 = __builtin_amdgcn_mfma_f32_16x16x32_bf16(ac0, b1, ar0, 0,0,0);
            ar1 = __builtin_amdgcn_mfma_f32_16x16x32_bf16(ac1, b1, ar1, 0,0,0);
            ar0 = __builtin_amdgcn_mfma_f32_16x16x32_bf16(ah0f, b4, ar0, 0,0,0);
            ar1 = __builtin_amdgcn_mfma_f32_16x16x32_bf16(ah1f, b4, ar1, 0,0,0);
            az0 = __builtin_amdgcn_mfma_f32_16x16x32_bf16(ac0, b2, az0, 0,0,0);
            az1 = __builtin_amdgcn_mfma_f32_16x16x32_bf16(ac1, b2, az1, 0,0,0);
            az0 = __builtin_amdgcn_mfma_f32_16x16x32_bf16(ah0f, b5, az0, 0,0,0);
            az1 = __builtin_amdgcn_mfma_f32_16x16x32_bf16(ah1f, b5, az1, 0,0,0);
            ai0 = __builtin_amdgcn_mfma_f32_16x16x32_bf16(ac0, b3, ai0, 0,0,0);
            ai1 = __builtin_amdgcn_mfma_f32_16x16x32_bf16(ac1, b3, ai1, 0,0,0);
            ah0 = __builtin_amdgcn_mfma_f32_16x16x32_bf16(ah0f, b6, ah0, 0,0,0);
            ah1 = __builtin_amdgcn_mfma_f32_16x16x32_bf16(ah1f, b6, ah1, 0,0,0);
        }
        const int f = t * 16 + (lane & 15);
        if (f < F_) {
            const float bir = gru_bih[f],        bhr = gru_bhh[f];
            const float biz = gru_bih[F_ + f],   bhz = gru_bhh[F_ + f];
            const float bin = gru_bih[2*F_ + f], bhn = gru_bhh[2*F_ + f];
            const float w2 = (mode == 0) ? alW2_next[f] : 0.0f;
            #pragma unroll
            for (int rg = 0; rg < 4; ++rg) {
                const int node = ((lane >> 4) << 2) + rg;
                {
                    const float r  = sigm(ar0[rg] + bir + bhr);
                    const float z  = sigm(az0[rg] + biz + bhz);
                    const float nn = fast_tanh(ai0[rg] + bin + r * (ah0[rg] + bhn));
                    const size_t o = (size_t)(node0 + node) * F_ + f;
                    const float h  = fmaxf((1.0f - z) * nn + z * cur_in[o], 0.0f);
                    dst[o] = h;
                    if (mode == 0) { dstb[o] = f2b(h); s2p0[rg] += h * w2; }
                }
                {
                    const int node2 = node + 16;
                    const float r  = sigm(ar1[rg] + bir + bhr);
                    const float z  = sigm(az1[rg] + biz + bhz);
                    const float nn = fast_tanh(ai1[rg] + bin + r * (ah1[rg] + bhn));
                    const size_t o = (size_t)(node0 + node2) * F_ + f;
                    const float h  = fmaxf((1.0f - z) * nn + z * cur_in[o], 0.0f);
                    dst[o] = h;
                    if (mode == 0) { dstb[o] = f2b(h); s2p1[rg] += h * w2; }
                }
            }
        }
    }

    if (mode == 0) {
        // reduce across the 16 lanes of each quarter-wave, then LDS-accumulate
        #pragma unroll
        for (int rg = 0; rg < 4; ++rg) {
            float v0 = s2p0[rg];
            v0 += __shfl_xor(v0, 1, 16); v0 += __shfl_xor(v0, 2, 16);
            v0 += __shfl_xor(v0, 4, 16); v0 += __shfl_xor(v0, 8, 16);
            float v1 = s2p1[rg];
            v1 += __shfl_xor(v1, 1, 16); v1 += __shfl_xor(v1, 2, 16);
            v1 += __shfl_xor(v1, 4, 16); v1 += __shfl_xor(v1, 8, 16);
            if ((lane & 15) == 0) {
                const int node = ((lane >> 4) << 2) + rg;
                atomicAdd(&s2acc[node], v0);
                atomicAdd(&s2acc[node + 16], v1);
            }
        }
        __syncthreads();
        if (tid < NTILE2) s2_next[node0 + tid] = s2acc[tid];
    }
}

extern "C" __attribute__((visibility("default")))
void kernel_launch(void* const* d_in, const int* in_sizes, int n_in,
                   void* d_out, int out_size, void* d_ws, size_t ws_size,
                   hipStream_t stream) {
    const float* atom_list = (const float*)d_in[0];
    const float* bond_list = (const float*)d_in[1];
    const int*   atom_deg  = (const int*)d_in[2];
    const int*   bond_deg  = (const int*)d_in[3];
    const float* atom_W    = (const float*)d_in[4];
    const float* atom_b    = (const float*)d_in[5];
    const float* nbr_W     = (const float*)d_in[6];
    const float* nbr_b     = (const float*)d_in[7];
    const float* align_W   = (const float*)d_in[8];
    const float* align_b   = (const float*)d_in[9];
    const float* attend_W  = (const float*)d_in[10];
    const float* attend_b  = (const float*)d_in[11];
    const float* gru_Wih   = (const float*)d_in[12];
    const float* gru_Whh   = (const float*)d_in[13];
    const float* gru_bih   = (const float*)d_in[14];
    const float* gru_bhh   = (const float*)d_in[15];

    float* ws   = (float*)d_ws;
    float* cur0 = ws;                       // NF fp32
    float* cur1 = ws + (size_t)NF;          // NF fp32
    float* s2b  = ws + (size_t)2*NF;        // NNODES fp32
    float* s2p  = s2b + NNODES;             // NPAIRS fp32
    float* asumg = s2p + NPAIRS;            // NNODES fp32
    unsigned short* cur0b = (unsigned short*)(asumg + NNODES);        // NF bf16
    unsigned short* cur1b = cur0b + (size_t)NF;                        // NF bf16
    unsigned short* PAb   = cur1b + (size_t)NF;                        // NF bf16
    unsigned short* PBb   = PAb   + (size_t)NF;                        // NF bf16
    unsigned short* mixg  = PBb   + (size_t)NF;                        // NF bf16
    unsigned short* WF    = mixg  + (size_t)NF;                        // 1.3 MB frags
    float* out  = (float*)d_out;

    prep_frags_kernel<<<dim3(NPREP + NBF), dim3(NT), 0, stream>>>(
        atom_list, bond_list, atom_W, atom_b, nbr_W,
        attend_W, gru_Wih, gru_Whh,
        cur0, cur0b, PAb, PBb, WF);

    pair_score_kernel<<<dim3(NPAIRS / PPB), dim3(NT), 0, stream>>>(
        atom_deg, bond_deg, PAb, PBb, align_W + F_, nbr_b, s2p);

    const dim3 ggrid(NNODES / NTILE);    // 2048
    const dim3 mgrid(NNODES / NTILE2);   // 1024
    const size_t rframe = (size_t)7 * NTL * KSTEPS * 64 * 8;  // shorts per round

    // round 0
    gather_kernel<<<ggrid, dim3(NT), 0, stream>>>(
        atom_deg, bond_deg, align_W, align_b, nbr_b,
        PAb, PBb, /*s2_tab*/s2p, cur0, cur0b, mixg, asumg, 0);

    gemm_kernel<<<mgrid, dim3(NT), 0, stream>>>(
        WF, attend_b, gru_bih, gru_bhh, mixg, asumg, cur0, cur0b,
        cur1, cur1b, /*alW2_next*/align_W + 2 * F_ + F_, /*s2_next*/s2b, 0);

    // round 1
    gather_kernel<<<ggrid, dim3(NT), 0, stream>>>(
        atom_deg, bond_deg, align_W + 2 * F_, align_b + 1, nbr_b,
        PAb, PBb, /*s2_tab*/s2b, cur1, cur1b, mixg, asumg, 1);

    gemm_kernel<<<mgrid, dim3(NT), 0, stream>>>(
        WF + rframe, attend_b + F_, gru_bih + 3 * F_, gru_bhh + 3 * F_,
        mixg, asumg, cur1, cur1b, out, /*dstb*/nullptr,
        /*alW2_next*/nullptr, /*s2_next*/nullptr, 1);
}

// Round 11
// 350.684 us; speedup vs baseline: 1.3565x; 1.3565x over previous
//
#include <hip/hip_runtime.h>

#define B_     256
#define L_     128
#define D_     6
#define F_     200
#define FA_    39
#define FB_    10
#define PAD_   127       // L-1 padding atom index
#define LMASK  127
#define NT     256
#define KC8    (F_/8)    // 25 short8 chunks per bf16 row
#define NTILE  16
#define NQ     (NTILE * D_)   // 96 pairs
#define NF     (B_ * L_ * F_) // 6,553,600 floats
#define MSZ    (F_ * F_)      // 40,000 floats per matrix
#define NNODES (B_ * L_)      // 32768
#define NPAIRS (NNODES * D_)  // 196608
#define KP     224            // K padded to 7*32 (MFMA reads k < 224)
#define KPP    232            // LDS row stride: 464B -> bank step 20 (conflict-free)
#define KSTEPS 7
#define NTL    13             // N tiles of 16 (200 -> 208)
#define FRAG_TOTAL (14 * NTL * KSTEPS * 64)
#define PN2    32
#define NPREP  (NNODES / PN2)                     // 1024 prep blocks
#define NBF    ((FRAG_TOTAL + NT - 1) / NT)       // 319 frag blocks

typedef __attribute__((ext_vector_type(8))) short sh8;
typedef __attribute__((ext_vector_type(4))) float f32x4;

__device__ __forceinline__ float lrelu(float x) { return x >= 0.0f ? x : 0.01f * x; }
__device__ __forceinline__ float sigm(float x)  { return 1.0f / (1.0f + __expf(-x)); }
__device__ __forceinline__ float fast_tanh(float x) {   // 1 - 2/(e^2x+1), sat-correct
    const float e = __expf(2.0f * x);
    return 1.0f - 2.0f / (e + 1.0f);
}
__device__ __forceinline__ unsigned short f2b(float x) {   // fp32 -> bf16 RNE
    unsigned int u = __float_as_uint(x);
    unsigned int r = (u + 0x7FFFu + ((u >> 16) & 1u)) >> 16;
    return (unsigned short)r;
}
__device__ __forceinline__ float b2f(unsigned short u) {
    return __uint_as_float(((unsigned int)u) << 16);
}
// A-fragment from LDS bf16 [NTILE][KPP]: A[m=lane&15][k=ks*32+quad*8+j]
#define AFRAG(arr, ks) (*(const sh8*)&arr[lane & 15][(ks) * 32 + ((lane >> 4) << 3)])
__device__ __forceinline__ sh8 bfrag(const unsigned short* __restrict__ WFr,
                                     int mat, int t, int ks, int lane) {
    return *(const sh8*)(WFr + ((((size_t)mat * NTL + t) * KSTEPS + ks) * 64 + lane) * 8);
}

// ========== fused: prep (blocks [0,NPREP)) + build_frags (blocks [NPREP,..)) ==========
__global__ __launch_bounds__(NT)
void prep_frags_kernel(const float* __restrict__ atom_list, const float* __restrict__ bond_list,
                       const float* __restrict__ atom_W, const float* __restrict__ atom_b,
                       const float* __restrict__ nbr_W,
                       const float* __restrict__ attend_W,
                       const float* __restrict__ gru_Wih,
                       const float* __restrict__ gru_Whh,
                       float* __restrict__ cur0, unsigned short* __restrict__ cur0b,
                       unsigned short* __restrict__ PA, unsigned short* __restrict__ PB,
                       unsigned short* __restrict__ WF)
{
    __shared__ float wsh[F_ * (FA_ + FB_)];   // 9800 floats = 39.2 KB
    const int tid = threadIdx.x;

    if (blockIdx.x >= NPREP) {
        // ---- build_frags part: bf16 B-fragments, 14 F×F matrices, zero-padded ----
        const int i = (blockIdx.x - NPREP) * NT + tid;
        if (i >= FRAG_TOTAL) return;
        const int lane = i & 63;
        int rest = i >> 6;
        const int ks = rest % KSTEPS; rest /= KSTEPS;
        const int t  = rest % NTL;
        const int m  = rest / NTL;
        const int n  = t * 16 + (lane & 15);
        const int k0 = ks * 32 + ((lane >> 4) << 3);
        const int r = m / 7, tt = m - r * 7;
        const float* src;
        if (tt == 0)      src = attend_W + (size_t)r * MSZ;
        else if (tt <= 3) src = gru_Wih + ((size_t)r * 3 + (tt - 1)) * MSZ;
        else              src = gru_Whh + ((size_t)r * 3 + (tt - 4)) * MSZ;
        unsigned short o[8];
        #pragma unroll
        for (int j = 0; j < 8; ++j) {
            const int k = k0 + j;
            const float v = (n < F_ && k < F_) ? src[(size_t)n * F_ + k] : 0.0f;
            o[j] = f2b(v);
        }
        uint4 w;
        w.x = (unsigned int)o[0] | ((unsigned int)o[1] << 16);
        w.y = (unsigned int)o[2] | ((unsigned int)o[3] << 16);
        w.z = (unsigned int)o[4] | ((unsigned int)o[5] << 16);
        w.w = (unsigned int)o[6] | ((unsigned int)o[7] << 16);
        ((uint4*)WF)[i] = w;
        return;
    }

    // ---- prep part: weight-stationary; lane owns column f, weights in regs ----
    const int node0 = blockIdx.x * PN2;
    const int f     = tid;
    const bool valid = (f < F_);
    const int fc    = valid ? f : 0;

    float wa[FA_];
    float wn[FA_ + FB_];

    for (int i = tid; i < F_ * FA_; i += NT) wsh[i] = atom_W[i];
    __syncthreads();
    #pragma unroll
    for (int k = 0; k < FA_; ++k) wa[k] = wsh[fc * FA_ + k];
    __syncthreads();
    for (int i = tid; i < F_ * (FA_ + FB_); i += NT) wsh[i] = nbr_W[i];
    __syncthreads();
    #pragma unroll
    for (int k = 0; k < FA_ + FB_; ++k) wn[k] = wsh[fc * (FA_ + FB_) + k];

    const float ab = atom_b[fc];

    for (int n = 0; n < PN2; ++n) {
        const float* __restrict__ ar = atom_list + (size_t)(node0 + n) * FA_;
        const float* __restrict__ br = bond_list + (size_t)(node0 + n) * FB_;
        float accA = ab, accPA = 0.0f, accPB = 0.0f;
        #pragma unroll
        for (int k = 0; k < FA_; ++k) {
            const float a = ar[k];          // wave-uniform -> scalar load
            accA  += a * wa[k];
            accPA += a * wn[k];
        }
        #pragma unroll
        for (int k = 0; k < FB_; ++k) accPB += br[k] * wn[FA_ + k];
        if (valid) {
            const size_t o = (size_t)(node0 + n) * F_ + f;
            const float c = lrelu(accA);
            cur0[o]  = c;
            cur0b[o] = f2b(c);
            PA[o]    = f2b(accPA);
            PB[o]    = f2b(accPB);
        }
    }
}

// ===== mode-0 pair-score table: s2p[q] = alW2 · lrelu(PA[nidx]+PB[bidx]+nbr_b) =====
#define PPB 32   // pairs per block, 8 lanes each
__global__ __launch_bounds__(NT)
void pair_score_kernel(const int* __restrict__ atom_degree,
                       const int* __restrict__ bond_degree,
                       const unsigned short* __restrict__ PA,
                       const unsigned short* __restrict__ PB,
                       const float* __restrict__ alW2, const float* __restrict__ nbr_b,
                       float* __restrict__ s2p)
{
    __shared__ float w_s[F_], b_s[F_];
    const int tid = threadIdx.x;
    if (tid < F_) { w_s[tid] = alW2[tid]; b_s[tid] = nbr_b[tid]; }
    // XCD-aligned swizzle: molecule m -> XCD m%8 (matches round_kernel)
    const int xcd = blockIdx.x & 7;
    const int j   = blockIdx.x >> 3;            // 0..767
    const int mol = (j / 24) * 8 + xcd;         // 24 blocks per molecule
    const int q0  = mol * (L_ * D_) + (j % 24) * PPB;
    const int q   = q0 + (tid >> 3);
    const int sub = tid & 7;
    const int nidx = atom_degree[q] & LMASK;
    const int bidx = bond_degree[q] & LMASK;
    const int bL   = mol * L_;
    const unsigned short* pa = PA + (size_t)(bL + nidx) * F_;
    const unsigned short* pb = PB + (size_t)(bL + bidx) * F_;
    __syncthreads();
    float s = 0.0f;
    for (int kk = sub; kk < KC8; kk += 8) {
        const sh8 pa8 = *(const sh8*)(pa + kk * 8);
        const sh8 pb8 = *(const sh8*)(pb + kk * 8);
        #pragma unroll
        for (int e = 0; e < 8; ++e)
            s += lrelu(b2f((unsigned short)pa8[e]) + b2f((unsigned short)pb8[e])
                       + b_s[kk * 8 + e]) * w_s[kk * 8 + e];
    }
    s += __shfl_xor(s, 1, 8); s += __shfl_xor(s, 2, 8); s += __shfl_xor(s, 4, 8);
    if (sub == 0) s2p[q] = s;
}

// ===================== round kernel (MFMA E/F, tile-sequential) =====================
// Best-known consolidation: r7 launch structure (fused s2 epilogue) + r6 Phase D
// (interleaved gathers, measured faster than batched) + bounds(256,4) (r8's
// (256,6) squeezed VGPR to 40 -> scratch spill, WRITE_SIZE 46->166 MB).
// NTILE=16 / 3-4 blocks/CU is the verified optimum: larger tiles thrash L2
// (r4/r9), higher occupancy spills (r8), kernel split loses phase overlap (r10).
__global__ __launch_bounds__(NT, 4)
void round_kernel(
    const int*   __restrict__ atom_degree,
    const int*   __restrict__ bond_degree,
    const float* __restrict__ align_W,       // [2F] this round (first half used)
    const float* __restrict__ align_b,       // [1]
    const unsigned short* __restrict__ WF,   // 7 fragment matrices this round
    const float* __restrict__ attend_b,
    const float* __restrict__ gru_bih,
    const float* __restrict__ gru_bhh,
    const float* __restrict__ nbr_b,         // mode0
    const unsigned short* __restrict__ PAb,  // mode0, bf16
    const unsigned short* __restrict__ PBb,  // mode0, bf16
    const float* __restrict__ s2_tab,        // mode0: per-pair table; mode1: per-node
    const float* __restrict__ cur_in,        // [B,L,F] fp32 (s1, epilogue)
    const unsigned short* __restrict__ cur_inb, // [B,L,F] bf16 shadow (A, mode1-D)
    float*       __restrict__ dst,
    unsigned short* __restrict__ dstb,       // bf16 shadow out (mode0 only)
    const float* __restrict__ alW2_next,     // mode0: round-1 alW2 for fused s2
    float*       __restrict__ s2_next,       // mode0: fused s2 output [NNODES]
    int mode)
{
    // XCD swizzle: all 8 tiles of a molecule share (blockIdx % 8) -> same XCD L2
    const int bid   = blockIdx.x;
    const int mol   = ((bid >> 6) << 3) | (bid & 7);
    const int tile  = (bid >> 3) & 7;
    const int node0 = mol * L_ + tile * NTILE;
    const int bL    = mol * L_;
    const int tid   = threadIdx.x;
    const int lane  = tid & 63;
    const int wave  = tid >> 6;

    __shared__ __align__(16) unsigned short curb  [NTILE][KPP];  // bf16 A-operands
    __shared__ __align__(16) unsigned short mixedb[NTILE][KPP];
    __shared__ __align__(16) unsigned short ctxb  [NTILE][KPP];
    __shared__ __align__(16) float nbrb_s[F_];
    __shared__ float sc_s [NQ];
    __shared__ float asum_s[NTILE];
    __shared__ float s1_s[NTILE];
    __shared__ float s2acc[NTILE];
    __shared__ int   nidx_s[NQ];
    __shared__ int   bidx_s[NQ];

    // zero K-pads [F_, KP) (MFMA reads them; pad x Wpad = 0 required)
    for (int idx = tid; idx < NTILE * (KP - F_); idx += NT) {
        const int n = idx / (KP - F_), k = F_ + idx % (KP - F_);
        curb[n][k] = 0; mixedb[n][k] = 0; ctxb[n][k] = 0;
    }
    if (tid < NTILE) s2acc[tid] = 0.0f;

    if (tid < NQ) {
        const int n = tid / D_, j = tid - n * D_;
        nidx_s[tid] = atom_degree[(node0 + n) * D_ + j] & LMASK;
        bidx_s[tid] = (mode == 0) ? (bond_degree[(node0 + n) * D_ + j] & LMASK) : 0;
    }
    if (mode == 0 && tid < F_) nbrb_s[tid] = nbr_b[tid];

    // Phase A: own cur rows -> bf16 LDS (pure 16B copy from bf16 shadow)
    for (int idx = tid; idx < NTILE * KC8; idx += NT) {
        const int n = idx / KC8, kk = idx - n * KC8;
        *(uint4*)&curb[n][kk * 8] =
            *(const uint4*)(cur_inb + (size_t)(node0 + n) * F_ + kk * 8);
    }

    // s1[n] = alW1 · cur[n] (16 lanes per node, fp32 — no LDS dep)
    {
        const int n = tid >> 4, sub = tid & 15;
        const float* crow = cur_in + (size_t)(node0 + n) * F_;
        float a = 0.0f;
        for (int f = sub; f < F_; f += 16) a += crow[f] * align_W[f];
        a += __shfl_xor(a, 1, 16); a += __shfl_xor(a, 2, 16);
        a += __shfl_xor(a, 4, 16); a += __shfl_xor(a, 8, 16);
        if (sub == 0) s1_s[n] = a;
    }
    __syncthreads();

    // Phase C: align scores — table lookup in BOTH modes
    if (tid < NQ) {
        const int n = tid / D_;
        const float s2v = (mode == 0)
            ? s2_tab[(size_t)(node0 + n) * D_ + (tid - n * D_)]
            : s2_tab[bL + nidx_s[tid]];
        float sc = lrelu(s1_s[n] + s2v + align_b[0]);
        if (nidx_s[tid] == PAD_) sc += -9.0e8f;
        sc_s[tid] = sc;
    }
    __syncthreads();

    // masked softmax over D per node
    if (tid < NTILE) {
        float m = sc_s[tid * D_];
        #pragma unroll
        for (int j = 1; j < D_; ++j) m = fmaxf(m, sc_s[tid * D_ + j]);
        float ex[D_]; float ssum = 0.0f;
        #pragma unroll
        for (int j = 0; j < D_; ++j) { ex[j] = __expf(sc_s[tid * D_ + j] - m); ssum += ex[j]; }
        const float inv = 1.0f / ssum;
        float as = 0.0f;
        #pragma unroll
        for (int j = 0; j < D_; ++j) {
            const float a = (nidx_s[tid * D_ + j] == PAD_) ? 0.0f : ex[j] * inv;
            sc_s[tid * D_ + j] = a;
            as += a;
        }
        asum_s[tid] = as;
    }
    __syncthreads();

    // Phase D: mixed[n] = sum_j attn_j * nbr_feat_j -> bf16 LDS (bf16 gathers,
    // r6 interleaved form — measured faster than r7's batched arrays)
    for (int idx = tid; idx < NTILE * KC8; idx += NT) {
        const int n = idx / KC8, kk = idx - n * KC8;
        const int c0 = kk * 8;
        float m[8];
        #pragma unroll
        for (int e = 0; e < 8; ++e) m[e] = 0.0f;
        if (mode == 0) {
            #pragma unroll
            for (int j = 0; j < D_; ++j) {
                const float a = sc_s[n * D_ + j];
                const sh8 pa8 = *(const sh8*)(PAb + (size_t)(bL + nidx_s[n*D_+j]) * F_ + c0);
                const sh8 pb8 = *(const sh8*)(PBb + (size_t)(bL + bidx_s[n*D_+j]) * F_ + c0);
                #pragma unroll
                for (int e = 0; e < 8; ++e)
                    m[e] += a * lrelu(b2f((unsigned short)pa8[e])
                                    + b2f((unsigned short)pb8[e]) + nbrb_s[c0 + e]);
            }
        } else {
            #pragma unroll
            for (int j = 0; j < D_; ++j) {
                const float a = sc_s[n * D_ + j];
                const sh8 v8 = *(const sh8*)(cur_inb + (size_t)(bL + nidx_s[n*D_+j]) * F_ + c0);
                #pragma unroll
                for (int e = 0; e < 8; ++e)
                    m[e] += a * b2f((unsigned short)v8[e]);
            }
        }
        uint4 w;
        w.x = (unsigned int)f2b(m[0]) | ((unsigned int)f2b(m[1]) << 16);
        w.y = (unsigned int)f2b(m[2]) | ((unsigned int)f2b(m[3]) << 16);
        w.z = (unsigned int)f2b(m[4]) | ((unsigned int)f2b(m[5]) << 16);
        w.w = (unsigned int)f2b(m[6]) | ((unsigned int)f2b(m[7]) << 16);
        *(uint4*)&mixedb[n][c0] = w;
    }
    __syncthreads();

    // ---- Phase E (MFMA, tile-sequential): ctx = elu(attend_W @ mixed + asum*b) ----
    for (int t = wave; t < NTL; t += 4) {
        f32x4 acc = {0.f, 0.f, 0.f, 0.f};
        #pragma unroll
        for (int ks = 0; ks < KSTEPS; ++ks)
            acc = __builtin_amdgcn_mfma_f32_16x16x32_bf16(
                AFRAG(mixedb, ks), bfrag(WF, 0, t, ks, lane), acc, 0, 0, 0);
        const int f = t * 16 + (lane & 15);
        if (f < F_) {
            const float bb = attend_b[f];
            #pragma unroll
            for (int rg = 0; rg < 4; ++rg) {
                const int node = ((lane >> 4) << 2) + rg;
                float c = acc[rg] + asum_s[node] * bb;
                c = (c > 0.0f) ? c : (__expf(c) - 1.0f);
                ctxb[node][f] = f2b(c);
            }
        }
    }
    __syncthreads();

    // ---- Phase F (MFMA, tile-sequential): GRU gates (+ fused next-round s2) ----
    float s2part[4] = {0.f, 0.f, 0.f, 0.f};
    for (int t = wave; t < NTL; t += 4) {
        f32x4 ar = {0.f,0.f,0.f,0.f}, az = {0.f,0.f,0.f,0.f};
        f32x4 ani = {0.f,0.f,0.f,0.f}, anh = {0.f,0.f,0.f,0.f};
        #pragma unroll
        for (int ks = 0; ks < KSTEPS; ++ks) {
            const sh8 ac = AFRAG(ctxb, ks);
            const sh8 ah = AFRAG(curb, ks);
            ar  = __builtin_amdgcn_mfma_f32_16x16x32_bf16(ac, bfrag(WF,1,t,ks,lane), ar, 0,0,0);
            ar  = __builtin_amdgcn_mfma_f32_16x16x32_bf16(ah, bfrag(WF,4,t,ks,lane), ar, 0,0,0);
            az  = __builtin_amdgcn_mfma_f32_16x16x32_bf16(ac, bfrag(WF,2,t,ks,lane), az, 0,0,0);
            az  = __builtin_amdgcn_mfma_f32_16x16x32_bf16(ah, bfrag(WF,5,t,ks,lane), az, 0,0,0);
            ani = __builtin_amdgcn_mfma_f32_16x16x32_bf16(ac, bfrag(WF,3,t,ks,lane), ani, 0,0,0);
            anh = __builtin_amdgcn_mfma_f32_16x16x32_bf16(ah, bfrag(WF,6,t,ks,lane), anh, 0,0,0);
        }
        const int f = t * 16 + (lane & 15);
        if (f < F_) {
            const float bir = gru_bih[f],        bhr = gru_bhh[f];
            const float biz = gru_bih[F_ + f],   bhz = gru_bhh[F_ + f];
            const float bin = gru_bih[2*F_ + f], bhn = gru_bhh[2*F_ + f];
            const float w2 = (mode == 0) ? alW2_next[f] : 0.0f;
            #pragma unroll
            for (int rg = 0; rg < 4; ++rg) {
                const int node = ((lane >> 4) << 2) + rg;
                const float r  = sigm(ar[rg] + bir + bhr);
                const float z  = sigm(az[rg] + biz + bhz);
                const float nn = fast_tanh(ani[rg] + bin + r * (anh[rg] + bhn));
                const size_t o = (size_t)(node0 + node) * F_ + f;
                const float cv = cur_in[o];
                const float h  = fmaxf((1.0f - z) * nn + z * cv, 0.0f);
                dst[o] = h;
                if (mode == 0) { dstb[o] = f2b(h); s2part[rg] += h * w2; }
            }
        }
    }

    if (mode == 0) {
        // reduce s2part across the 16 lanes of each quarter-wave, then LDS-accumulate
        #pragma unroll
        for (int rg = 0; rg < 4; ++rg) {
            float v = s2part[rg];
            v += __shfl_xor(v, 1, 16); v += __shfl_xor(v, 2, 16);
            v += __shfl_xor(v, 4, 16); v += __shfl_xor(v, 8, 16);
            if ((lane & 15) == 0) atomicAdd(&s2acc[((lane >> 4) << 2) + rg], v);
        }
        __syncthreads();
        if (tid < NTILE) s2_next[node0 + tid] = s2acc[tid];
    }
}

extern "C" __attribute__((visibility("default")))
void kernel_launch(void* const* d_in, const int* in_sizes, int n_in,
                   void* d_out, int out_size, void* d_ws, size_t ws_size,
                   hipStream_t stream) {
    const float* atom_list = (const float*)d_in[0];
    const float* bond_list = (const float*)d_in[1];
    const int*   atom_deg  = (const int*)d_in[2];
    const int*   bond_deg  = (const int*)d_in[3];
    const float* atom_W    = (const float*)d_in[4];
    const float* atom_b    = (const float*)d_in[5];
    const float* nbr_W     = (const float*)d_in[6];
    const float* nbr_b     = (const float*)d_in[7];
    const float* align_W   = (const float*)d_in[8];
    const float* align_b   = (const float*)d_in[9];
    const float* attend_W  = (const float*)d_in[10];
    const float* attend_b  = (const float*)d_in[11];
    const float* gru_Wih   = (const float*)d_in[12];
    const float* gru_Whh   = (const float*)d_in[13];
    const float* gru_bih   = (const float*)d_in[14];
    const float* gru_bhh   = (const float*)d_in[15];

    float* ws   = (float*)d_ws;
    float* cur0 = ws;                       // NF fp32
    float* cur1 = ws + (size_t)NF;          // NF fp32
    float* s2b  = ws + (size_t)2*NF;        // NNODES fp32
    float* s2p  = s2b + NNODES;             // NPAIRS fp32
    unsigned short* cur0b = (unsigned short*)(s2p + NPAIRS);          // NF bf16
    unsigned short* cur1b = cur0b + (size_t)NF;                        // NF bf16
    unsigned short* PAb   = cur1b + (size_t)NF;                        // NF bf16
    unsigned short* PBb   = PAb   + (size_t)NF;                        // NF bf16
    unsigned short* WF    = PBb   + (size_t)NF;                        // 1.3 MB frags
    float* out  = (float*)d_out;

    prep_frags_kernel<<<dim3(NPREP + NBF), dim3(NT), 0, stream>>>(
        atom_list, bond_list, atom_W, atom_b, nbr_W,
        attend_W, gru_Wih, gru_Whh,
        cur0, cur0b, PAb, PBb, WF);

    pair_score_kernel<<<dim3(NPAIRS / PPB), dim3(NT), 0, stream>>>(
        atom_deg, bond_deg, PAb, PBb, align_W + F_, nbr_b, s2p);

    const dim3 grid(NNODES / NTILE);
    const size_t rframe = (size_t)7 * NTL * KSTEPS * 64 * 8;  // shorts per round

    round_kernel<<<grid, dim3(NT), 0, stream>>>(
        atom_deg, bond_deg, align_W, align_b,
        WF, attend_b, gru_bih, gru_bhh,
        nbr_b, PAb, PBb, /*s2_tab*/s2p, cur0, cur0b, cur1, cur1b,
        /*alW2_next*/align_W + 2 * F_ + F_, /*s2_next*/s2b, 0);

    round_kernel<<<grid, dim3(NT), 0, stream>>>(
        atom_deg, bond_deg, align_W + 2 * F_, align_b + 1,
        WF + rframe, attend_b + F_, gru_bih + 3 * F_, gru_bhh + 3 * F_,
        nbr_b, PAb, PBb, s2b, cur1, cur1b, out, /*dstb*/nullptr,
        /*alW2_next*/nullptr, /*s2_next*/nullptr, 1);
}

// Round 12
// 340.075 us; speedup vs baseline: 1.3989x; 1.0312x over previous
//
#include <hip/hip_runtime.h>

#define B_     256
#define L_     128
#define D_     6
#define F_     200
#define FA_    39
#define FB_    10
#define PAD_   127       // L-1 padding atom index
#define LMASK  127
#define NT     256
#define KC8    (F_/8)    // 25 short8 chunks per bf16 row
#define NTILE  16
#define NQ     (NTILE * D_)   // 96 pairs
#define NF     (B_ * L_ * F_) // 6,553,600 floats
#define MSZ    (F_ * F_)      // 40,000 floats per matrix
#define NNODES (B_ * L_)      // 32768
#define NPAIRS (NNODES * D_)  // 196608
#define KP     224            // K padded to 7*32 (MFMA reads k < 224)
#define KPP    232            // LDS row stride: 464B -> bank step 20 (conflict-free)
#define KSTEPS 7
#define NTL    13             // N tiles of 16 (200 -> 208)
#define FRAG_TOTAL (14 * NTL * KSTEPS * 64)
#define PN2    32
#define NPREP  (NNODES / PN2)                     // 1024 prep blocks
#define NBF    ((FRAG_TOTAL + NT - 1) / NT)       // 319 frag blocks

typedef __attribute__((ext_vector_type(8))) short sh8;
typedef __attribute__((ext_vector_type(4))) float f32x4;

__device__ __forceinline__ float lrelu(float x) { return x >= 0.0f ? x : 0.01f * x; }
__device__ __forceinline__ float sigm(float x)  { return 1.0f / (1.0f + __expf(-x)); }
__device__ __forceinline__ float fast_tanh(float x) {   // 1 - 2/(e^2x+1), sat-correct
    const float e = __expf(2.0f * x);
    return 1.0f - 2.0f / (e + 1.0f);
}
__device__ __forceinline__ unsigned short f2b(float x) {   // fp32 -> bf16 RNE
    unsigned int u = __float_as_uint(x);
    unsigned int r = (u + 0x7FFFu + ((u >> 16) & 1u)) >> 16;
    return (unsigned short)r;
}
__device__ __forceinline__ float b2f(unsigned short u) {
    return __uint_as_float(((unsigned int)u) << 16);
}
// A-fragment from LDS bf16 [NTILE][KPP]: A[m=lane&15][k=ks*32+quad*8+j]
#define AFRAG(arr, ks) (*(const sh8*)&arr[lane & 15][(ks) * 32 + ((lane >> 4) << 3)])
__device__ __forceinline__ sh8 bfrag(const unsigned short* __restrict__ WFr,
                                     int mat, int t, int ks, int lane) {
    return *(const sh8*)(WFr + ((((size_t)mat * NTL + t) * KSTEPS + ks) * 64 + lane) * 8);
}

// ========== fused: prep (blocks [0,NPREP)) + build_frags (blocks [NPREP,..)) ==========
__global__ __launch_bounds__(NT)
void prep_frags_kernel(const float* __restrict__ atom_list, const float* __restrict__ bond_list,
                       const float* __restrict__ atom_W, const float* __restrict__ atom_b,
                       const float* __restrict__ nbr_W,
                       const float* __restrict__ attend_W,
                       const float* __restrict__ gru_Wih,
                       const float* __restrict__ gru_Whh,
                       float* __restrict__ cur0, unsigned short* __restrict__ cur0b,
                       unsigned short* __restrict__ PA, unsigned short* __restrict__ PB,
                       unsigned short* __restrict__ WF)
{
    __shared__ float wsh[F_ * (FA_ + FB_)];   // 9800 floats = 39.2 KB
    const int tid = threadIdx.x;

    if (blockIdx.x >= NPREP) {
        // ---- build_frags part: bf16 B-fragments, 14 F×F matrices, zero-padded ----
        const int i = (blockIdx.x - NPREP) * NT + tid;
        if (i >= FRAG_TOTAL) return;
        const int lane = i & 63;
        int rest = i >> 6;
        const int ks = rest % KSTEPS; rest /= KSTEPS;
        const int t  = rest % NTL;
        const int m  = rest / NTL;
        const int n  = t * 16 + (lane & 15);
        const int k0 = ks * 32 + ((lane >> 4) << 3);
        const int r = m / 7, tt = m - r * 7;
        const float* src;
        if (tt == 0)      src = attend_W + (size_t)r * MSZ;
        else if (tt <= 3) src = gru_Wih + ((size_t)r * 3 + (tt - 1)) * MSZ;
        else              src = gru_Whh + ((size_t)r * 3 + (tt - 4)) * MSZ;
        unsigned short o[8];
        #pragma unroll
        for (int j = 0; j < 8; ++j) {
            const int k = k0 + j;
            const float v = (n < F_ && k < F_) ? src[(size_t)n * F_ + k] : 0.0f;
            o[j] = f2b(v);
        }
        uint4 w;
        w.x = (unsigned int)o[0] | ((unsigned int)o[1] << 16);
        w.y = (unsigned int)o[2] | ((unsigned int)o[3] << 16);
        w.z = (unsigned int)o[4] | ((unsigned int)o[5] << 16);
        w.w = (unsigned int)o[6] | ((unsigned int)o[7] << 16);
        ((uint4*)WF)[i] = w;
        return;
    }

    // ---- prep part: weight-stationary; lane owns column f, weights in regs ----
    const int node0 = blockIdx.x * PN2;
    const int f     = tid;
    const bool valid = (f < F_);
    const int fc    = valid ? f : 0;

    float wa[FA_];
    float wn[FA_ + FB_];

    for (int i = tid; i < F_ * FA_; i += NT) wsh[i] = atom_W[i];
    __syncthreads();
    #pragma unroll
    for (int k = 0; k < FA_; ++k) wa[k] = wsh[fc * FA_ + k];
    __syncthreads();
    for (int i = tid; i < F_ * (FA_ + FB_); i += NT) wsh[i] = nbr_W[i];
    __syncthreads();
    #pragma unroll
    for (int k = 0; k < FA_ + FB_; ++k) wn[k] = wsh[fc * (FA_ + FB_) + k];
    __syncthreads();   // wn copies done -> wsh is free

    // stage the 32 node input rows into wsh (contiguous -> fully coalesced);
    // the node loop then reads LDS broadcasts instead of a serial chain of
    // ~200cy wave-uniform global loads (the old latency limiter).
    {
        const float* asrc = atom_list + (size_t)node0 * FA_;
        for (int i = tid; i < PN2 * FA_; i += NT) wsh[i] = asrc[i];
        const float* bsrc = bond_list + (size_t)node0 * FB_;
        for (int i = tid; i < PN2 * FB_; i += NT) wsh[PN2 * FA_ + i] = bsrc[i];
    }
    __syncthreads();

    const float ab = atom_b[fc];

    for (int n = 0; n < PN2; ++n) {
        const float* __restrict__ ar = &wsh[n * FA_];
        const float* __restrict__ br = &wsh[PN2 * FA_ + n * FB_];
        float accA = ab, accPA = 0.0f, accPB = 0.0f;
        #pragma unroll
        for (int k = 0; k < FA_; ++k) {
            const float a = ar[k];          // LDS broadcast (same addr all lanes)
            accA  += a * wa[k];
            accPA += a * wn[k];
        }
        #pragma unroll
        for (int k = 0; k < FB_; ++k) accPB += br[k] * wn[FA_ + k];
        if (valid) {
            const size_t o = (size_t)(node0 + n) * F_ + f;
            const float c = lrelu(accA);
            cur0[o]  = c;
            cur0b[o] = f2b(c);
            PA[o]    = f2b(accPA);
            PB[o]    = f2b(accPB);
        }
    }
}

// ===== mode-0 pair-score table: s2p[q] = alW2 · lrelu(PA[nidx]+PB[bidx]+nbr_b) =====
#define PPB 32   // pairs per block, 8 lanes each
__global__ __launch_bounds__(NT)
void pair_score_kernel(const int* __restrict__ atom_degree,
                       const int* __restrict__ bond_degree,
                       const unsigned short* __restrict__ PA,
                       const unsigned short* __restrict__ PB,
                       const float* __restrict__ alW2, const float* __restrict__ nbr_b,
                       float* __restrict__ s2p)
{
    __shared__ float w_s[F_], b_s[F_];
    const int tid = threadIdx.x;
    if (tid < F_) { w_s[tid] = alW2[tid]; b_s[tid] = nbr_b[tid]; }
    // XCD-aligned swizzle: molecule m -> XCD m%8 (matches round_kernel)
    const int xcd = blockIdx.x & 7;
    const int j   = blockIdx.x >> 3;            // 0..767
    const int mol = (j / 24) * 8 + xcd;         // 24 blocks per molecule
    const int q0  = mol * (L_ * D_) + (j % 24) * PPB;
    const int q   = q0 + (tid >> 3);
    const int sub = tid & 7;
    const int nidx = atom_degree[q] & LMASK;
    const int bidx = bond_degree[q] & LMASK;
    const int bL   = mol * L_;
    const unsigned short* pa = PA + (size_t)(bL + nidx) * F_;
    const unsigned short* pb = PB + (size_t)(bL + bidx) * F_;
    __syncthreads();
    float s = 0.0f;
    for (int kk = sub; kk < KC8; kk += 8) {
        const sh8 pa8 = *(const sh8*)(pa + kk * 8);
        const sh8 pb8 = *(const sh8*)(pb + kk * 8);
        #pragma unroll
        for (int e = 0; e < 8; ++e)
            s += lrelu(b2f((unsigned short)pa8[e]) + b2f((unsigned short)pb8[e])
                       + b_s[kk * 8 + e]) * w_s[kk * 8 + e];
    }
    s += __shfl_xor(s, 1, 8); s += __shfl_xor(s, 2, 8); s += __shfl_xor(s, 4, 8);
    if (sub == 0) s2p[q] = s;
}

// ===================== round kernel (MFMA E/F, tile-sequential) =====================
// r11 structure + fused s1/score/softmax phase: one wave-parallel pass in the
// 16-lanes-per-node layout (s1 reduce leaves s1 in-register; lanes 0-5 score
// their pair inline; width-8 shuffle softmax). Cuts barriers 6 -> 4 and removes
// the two mostly-idle phases (C: 96 threads, softmax: 16 threads).
__global__ __launch_bounds__(NT, 4)
void round_kernel(
    const int*   __restrict__ atom_degree,
    const int*   __restrict__ bond_degree,
    const float* __restrict__ align_W,       // [2F] this round (first half used)
    const float* __restrict__ align_b,       // [1]
    const unsigned short* __restrict__ WF,   // 7 fragment matrices this round
    const float* __restrict__ attend_b,
    const float* __restrict__ gru_bih,
    const float* __restrict__ gru_bhh,
    const float* __restrict__ nbr_b,         // mode0
    const unsigned short* __restrict__ PAb,  // mode0, bf16
    const unsigned short* __restrict__ PBb,  // mode0, bf16
    const float* __restrict__ s2_tab,        // mode0: per-pair table; mode1: per-node
    const float* __restrict__ cur_in,        // [B,L,F] fp32 (s1, epilogue)
    const unsigned short* __restrict__ cur_inb, // [B,L,F] bf16 shadow (A, mode1-D)
    float*       __restrict__ dst,
    unsigned short* __restrict__ dstb,       // bf16 shadow out (mode0 only)
    const float* __restrict__ alW2_next,     // mode0: round-1 alW2 for fused s2
    float*       __restrict__ s2_next,       // mode0: fused s2 output [NNODES]
    int mode)
{
    // XCD swizzle: all 8 tiles of a molecule share (blockIdx % 8) -> same XCD L2
    const int bid   = blockIdx.x;
    const int mol   = ((bid >> 6) << 3) | (bid & 7);
    const int tile  = (bid >> 3) & 7;
    const int node0 = mol * L_ + tile * NTILE;
    const int bL    = mol * L_;
    const int tid   = threadIdx.x;
    const int lane  = tid & 63;
    const int wave  = tid >> 6;

    __shared__ __align__(16) unsigned short curb  [NTILE][KPP];  // bf16 A-operands
    __shared__ __align__(16) unsigned short mixedb[NTILE][KPP];
    __shared__ __align__(16) unsigned short ctxb  [NTILE][KPP];
    __shared__ __align__(16) float nbrb_s[F_];
    __shared__ float sc_s [NQ];
    __shared__ float asum_s[NTILE];
    __shared__ float s2acc[NTILE];
    __shared__ int   nidx_s[NQ];
    __shared__ int   bidx_s[NQ];

    // zero K-pads [F_, KP) (MFMA reads them; pad x Wpad = 0 required)
    for (int idx = tid; idx < NTILE * (KP - F_); idx += NT) {
        const int n = idx / (KP - F_), k = F_ + idx % (KP - F_);
        curb[n][k] = 0; mixedb[n][k] = 0; ctxb[n][k] = 0;
    }
    if (tid < NTILE) s2acc[tid] = 0.0f;
    if (mode == 0 && tid < F_) nbrb_s[tid] = nbr_b[tid];

    // Phase A: own cur rows -> bf16 LDS (pure 16B copy from bf16 shadow)
    for (int idx = tid; idx < NTILE * KC8; idx += NT) {
        const int n = idx / KC8, kk = idx - n * KC8;
        *(uint4*)&curb[n][kk * 8] =
            *(const uint4*)(cur_inb + (size_t)(node0 + n) * F_ + kk * 8);
    }

    // Fused s1 + align-score + softmax (16 lanes per node, no intermediate barriers)
    {
        const int n = tid >> 4, sub = tid & 15;
        const float* crow = cur_in + (size_t)(node0 + n) * F_;
        float s1 = 0.0f;
        for (int f = sub; f < F_; f += 16) s1 += crow[f] * align_W[f];
        s1 += __shfl_xor(s1, 1, 16); s1 += __shfl_xor(s1, 2, 16);
        s1 += __shfl_xor(s1, 4, 16); s1 += __shfl_xor(s1, 8, 16);
        // lanes 0..5 score their pair; 6..15 hold -inf filler
        float sc = -3.0e38f;
        int nidx = 0, bidx = 0;
        if (sub < D_) {
            nidx = atom_degree[(node0 + n) * D_ + sub] & LMASK;
            if (mode == 0) bidx = bond_degree[(node0 + n) * D_ + sub] & LMASK;
            const float s2v = (mode == 0)
                ? s2_tab[(size_t)(node0 + n) * D_ + sub]
                : s2_tab[bL + nidx];
            sc = lrelu(s1 + s2v + align_b[0]);
            if (nidx == PAD_) sc += -9.0e8f;
        }
        // width-8 softmax (lanes 6,7: exp(-inf)=0 contribute nothing)
        float mx = sc;
        mx = fmaxf(mx, __shfl_xor(mx, 1, 8));
        mx = fmaxf(mx, __shfl_xor(mx, 2, 8));
        mx = fmaxf(mx, __shfl_xor(mx, 4, 8));
        const float ex = __expf(sc - mx);
        float ssum = ex;
        ssum += __shfl_xor(ssum, 1, 8);
        ssum += __shfl_xor(ssum, 2, 8);
        ssum += __shfl_xor(ssum, 4, 8);
        const float inv = 1.0f / ssum;
        const float aw = (sub < D_ && nidx != PAD_) ? ex * inv : 0.0f;
        if (sub < D_) {
            sc_s[n * D_ + sub]   = aw;
            nidx_s[n * D_ + sub] = nidx;
            if (mode == 0) bidx_s[n * D_ + sub] = bidx;
        }
        float as = aw;
        as += __shfl_xor(as, 1, 8);
        as += __shfl_xor(as, 2, 8);
        as += __shfl_xor(as, 4, 8);
        if (sub == 0) asum_s[n] = as;
    }
    __syncthreads();

    // Phase D: mixed[n] = sum_j attn_j * nbr_feat_j -> bf16 LDS (bf16 gathers)
    for (int idx = tid; idx < NTILE * KC8; idx += NT) {
        const int n = idx / KC8, kk = idx - n * KC8;
        const int c0 = kk * 8;
        float m[8];
        #pragma unroll
        for (int e = 0; e < 8; ++e) m[e] = 0.0f;
        if (mode == 0) {
            #pragma unroll
            for (int j = 0; j < D_; ++j) {
                const float a = sc_s[n * D_ + j];
                const sh8 pa8 = *(const sh8*)(PAb + (size_t)(bL + nidx_s[n*D_+j]) * F_ + c0);
                const sh8 pb8 = *(const sh8*)(PBb + (size_t)(bL + bidx_s[n*D_+j]) * F_ + c0);
                #pragma unroll
                for (int e = 0; e < 8; ++e)
                    m[e] += a * lrelu(b2f((unsigned short)pa8[e])
                                    + b2f((unsigned short)pb8[e]) + nbrb_s[c0 + e]);
            }
        } else {
            #pragma unroll
            for (int j = 0; j < D_; ++j) {
                const float a = sc_s[n * D_ + j];
                const sh8 v8 = *(const sh8*)(cur_inb + (size_t)(bL + nidx_s[n*D_+j]) * F_ + c0);
                #pragma unroll
                for (int e = 0; e < 8; ++e)
                    m[e] += a * b2f((unsigned short)v8[e]);
            }
        }
        uint4 w;
        w.x = (unsigned int)f2b(m[0]) | ((unsigned int)f2b(m[1]) << 16);
        w.y = (unsigned int)f2b(m[2]) | ((unsigned int)f2b(m[3]) << 16);
        w.z = (unsigned int)f2b(m[4]) | ((unsigned int)f2b(m[5]) << 16);
        w.w = (unsigned int)f2b(m[6]) | ((unsigned int)f2b(m[7]) << 16);
        *(uint4*)&mixedb[n][c0] = w;
    }
    __syncthreads();

    // ---- Phase E (MFMA, tile-sequential): ctx = elu(attend_W @ mixed + asum*b) ----
    for (int t = wave; t < NTL; t += 4) {
        f32x4 acc = {0.f, 0.f, 0.f, 0.f};
        #pragma unroll
        for (int ks = 0; ks < KSTEPS; ++ks)
            acc = __builtin_amdgcn_mfma_f32_16x16x32_bf16(
                AFRAG(mixedb, ks), bfrag(WF, 0, t, ks, lane), acc, 0, 0, 0);
        const int f = t * 16 + (lane & 15);
        if (f < F_) {
            const float bb = attend_b[f];
            #pragma unroll
            for (int rg = 0; rg < 4; ++rg) {
                const int node = ((lane >> 4) << 2) + rg;
                float c = acc[rg] + asum_s[node] * bb;
                c = (c > 0.0f) ? c : (__expf(c) - 1.0f);
                ctxb[node][f] = f2b(c);
            }
        }
    }
    __syncthreads();

    // ---- Phase F (MFMA, tile-sequential): GRU gates (+ fused next-round s2) ----
    float s2part[4] = {0.f, 0.f, 0.f, 0.f};
    for (int t = wave; t < NTL; t += 4) {
        f32x4 ar = {0.f,0.f,0.f,0.f}, az = {0.f,0.f,0.f,0.f};
        f32x4 ani = {0.f,0.f,0.f,0.f}, anh = {0.f,0.f,0.f,0.f};
        #pragma unroll
        for (int ks = 0; ks < KSTEPS; ++ks) {
            const sh8 ac = AFRAG(ctxb, ks);
            const sh8 ah = AFRAG(curb, ks);
            ar  = __builtin_amdgcn_mfma_f32_16x16x32_bf16(ac, bfrag(WF,1,t,ks,lane), ar, 0,0,0);
            ar  = __builtin_amdgcn_mfma_f32_16x16x32_bf16(ah, bfrag(WF,4,t,ks,lane), ar, 0,0,0);
            az  = __builtin_amdgcn_mfma_f32_16x16x32_bf16(ac, bfrag(WF,2,t,ks,lane), az, 0,0,0);
            az  = __builtin_amdgcn_mfma_f32_16x16x32_bf16(ah, bfrag(WF,5,t,ks,lane), az, 0,0,0);
            ani = __builtin_amdgcn_mfma_f32_16x16x32_bf16(ac, bfrag(WF,3,t,ks,lane), ani, 0,0,0);
            anh = __builtin_amdgcn_mfma_f32_16x16x32_bf16(ah, bfrag(WF,6,t,ks,lane), anh, 0,0,0);
        }
        const int f = t * 16 + (lane & 15);
        if (f < F_) {
            const float bir = gru_bih[f],        bhr = gru_bhh[f];
            const float biz = gru_bih[F_ + f],   bhz = gru_bhh[F_ + f];
            const float bin = gru_bih[2*F_ + f], bhn = gru_bhh[2*F_ + f];
            const float w2 = (mode == 0) ? alW2_next[f] : 0.0f;
            #pragma unroll
            for (int rg = 0; rg < 4; ++rg) {
                const int node = ((lane >> 4) << 2) + rg;
                const float r  = sigm(ar[rg] + bir + bhr);
                const float z  = sigm(az[rg] + biz + bhz);
                const float nn = fast_tanh(ani[rg] + bin + r * (anh[rg] + bhn));
                const size_t o = (size_t)(node0 + node) * F_ + f;
                const float cv = cur_in[o];
                const float h  = fmaxf((1.0f - z) * nn + z * cv, 0.0f);
                dst[o] = h;
                if (mode == 0) { dstb[o] = f2b(h); s2part[rg] += h * w2; }
            }
        }
    }

    if (mode == 0) {
        // reduce s2part across the 16 lanes of each quarter-wave, then LDS-accumulate
        #pragma unroll
        for (int rg = 0; rg < 4; ++rg) {
            float v = s2part[rg];
            v += __shfl_xor(v, 1, 16); v += __shfl_xor(v, 2, 16);
            v += __shfl_xor(v, 4, 16); v += __shfl_xor(v, 8, 16);
            if ((lane & 15) == 0) atomicAdd(&s2acc[((lane >> 4) << 2) + rg], v);
        }
        __syncthreads();
        if (tid < NTILE) s2_next[node0 + tid] = s2acc[tid];
    }
}

extern "C" __attribute__((visibility("default")))
void kernel_launch(void* const* d_in, const int* in_sizes, int n_in,
                   void* d_out, int out_size, void* d_ws, size_t ws_size,
                   hipStream_t stream) {
    const float* atom_list = (const float*)d_in[0];
    const float* bond_list = (const float*)d_in[1];
    const int*   atom_deg  = (const int*)d_in[2];
    const int*   bond_deg  = (const int*)d_in[3];
    const float* atom_W    = (const float*)d_in[4];
    const float* atom_b    = (const float*)d_in[5];
    const float* nbr_W     = (const float*)d_in[6];
    const float* nbr_b     = (const float*)d_in[7];
    const float* align_W   = (const float*)d_in[8];
    const float* align_b   = (const float*)d_in[9];
    const float* attend_W  = (const float*)d_in[10];
    const float* attend_b  = (const float*)d_in[11];
    const float* gru_Wih   = (const float*)d_in[12];
    const float* gru_Whh   = (const float*)d_in[13];
    const float* gru_bih   = (const float*)d_in[14];
    const float* gru_bhh   = (const float*)d_in[15];

    float* ws   = (float*)d_ws;
    float* cur0 = ws;                       // NF fp32
    float* cur1 = ws + (size_t)NF;          // NF fp32
    float* s2b  = ws + (size_t)2*NF;        // NNODES fp32
    float* s2p  = s2b + NNODES;             // NPAIRS fp32
    unsigned short* cur0b = (unsigned short*)(s2p + NPAIRS);          // NF bf16
    unsigned short* cur1b = cur0b + (size_t)NF;                        // NF bf16
    unsigned short* PAb   = cur1b + (size_t)NF;                        // NF bf16
    unsigned short* PBb   = PAb   + (size_t)NF;                        // NF bf16
    unsigned short* WF    = PBb   + (size_t)NF;                        // 1.3 MB frags
    float* out  = (float*)d_out;

    prep_frags_kernel<<<dim3(NPREP + NBF), dim3(NT), 0, stream>>>(
        atom_list, bond_list, atom_W, atom_b, nbr_W,
        attend_W, gru_Wih, gru_Whh,
        cur0, cur0b, PAb, PBb, WF);

    pair_score_kernel<<<dim3(NPAIRS / PPB), dim3(NT), 0, stream>>>(
        atom_deg, bond_deg, PAb, PBb, align_W + F_, nbr_b, s2p);

    const dim3 grid(NNODES / NTILE);
    const size_t rframe = (size_t)7 * NTL * KSTEPS * 64 * 8;  // shorts per round

    round_kernel<<<grid, dim3(NT), 0, stream>>>(
        atom_deg, bond_deg, align_W, align_b,
        WF, attend_b, gru_bih, gru_bhh,
        nbr_b, PAb, PBb, /*s2_tab*/s2p, cur0, cur0b, cur1, cur1b,
        /*alW2_next*/align_W + 2 * F_ + F_, /*s2_next*/s2b, 0);

    round_kernel<<<grid, dim3(NT), 0, stream>>>(
        atom_deg, bond_deg, align_W + 2 * F_, align_b + 1,
        WF + rframe, attend_b + F_, gru_bih + 3 * F_, gru_bhh + 3 * F_,
        nbr_b, PAb, PBb, s2b, cur1, cur1b, out, /*dstb*/nullptr,
        /*alW2_next*/nullptr, /*s2_next*/nullptr, 1);
}

// Round 13
// 313.911 us; speedup vs baseline: 1.5155x; 1.0834x over previous
//
#include <hip/hip_runtime.h>

#define B_     256
#define L_     128
#define D_     6
#define F_     200
#define FA_    39
#define FB_    10
#define PAD_   127       // L-1 padding atom index
#define LMASK  127
#define NT     256
#define KC8    (F_/8)    // 25 short8 chunks per bf16 row
#define NTILE  16
#define NQ     (NTILE * D_)   // 96 pairs
#define NF     (B_ * L_ * F_) // 6,553,600 floats
#define MSZ    (F_ * F_)      // 40,000 floats per matrix
#define NNODES (B_ * L_)      // 32768
#define NPAIRS (NNODES * D_)  // 196608
#define KP     224            // K padded to 7*32 (MFMA reads k < 224)
#define KPP    232            // LDS row stride: 464B -> bank step 20 (conflict-free)
#define KSTEPS 7
#define NTL    13             // N tiles of 16 (200 -> 208)
#define FRAG_TOTAL (14 * NTL * KSTEPS * 64)
#define PN2    16
#define NPREP  (NNODES / PN2)                     // 2048 prep blocks
#define NBF    ((FRAG_TOTAL + NT - 1) / NT)       // 319 frag blocks

typedef __attribute__((ext_vector_type(8))) short sh8;
typedef __attribute__((ext_vector_type(4))) float f32x4;

__device__ __forceinline__ float lrelu(float x) { return x >= 0.0f ? x : 0.01f * x; }
__device__ __forceinline__ float sigm(float x)  { return 1.0f / (1.0f + __expf(-x)); }
__device__ __forceinline__ float fast_tanh(float x) {   // 1 - 2/(e^2x+1), sat-correct
    const float e = __expf(2.0f * x);
    return 1.0f - 2.0f / (e + 1.0f);
}
__device__ __forceinline__ unsigned short f2b(float x) {   // fp32 -> bf16 RNE
    unsigned int u = __float_as_uint(x);
    unsigned int r = (u + 0x7FFFu + ((u >> 16) & 1u)) >> 16;
    return (unsigned short)r;
}
__device__ __forceinline__ float b2f(unsigned short u) {
    return __uint_as_float(((unsigned int)u) << 16);
}
// A-fragment from LDS bf16 [NTILE][KPP]: A[m=lane&15][k=ks*32+quad*8+j]
#define AFRAG(arr, ks) (*(const sh8*)&arr[lane & 15][(ks) * 32 + ((lane >> 4) << 3)])
__device__ __forceinline__ sh8 bfrag(const unsigned short* __restrict__ WFr,
                                     int mat, int t, int ks, int lane) {
    return *(const sh8*)(WFr + ((((size_t)mat * NTL + t) * KSTEPS + ks) * 64 + lane) * 8);
}

// ========== fused: prep (blocks [0,NPREP)) + build_frags (blocks [NPREP,..)) ==========
// PN2=16 (was 32): halves the serial node loop, doubles TLP for the
// latency-bound LDS-broadcast accumulate chain. fp32 cur0 output dropped —
// everything downstream consumes the bf16 shadow.
__global__ __launch_bounds__(NT)
void prep_frags_kernel(const float* __restrict__ atom_list, const float* __restrict__ bond_list,
                       const float* __restrict__ atom_W, const float* __restrict__ atom_b,
                       const float* __restrict__ nbr_W,
                       const float* __restrict__ attend_W,
                       const float* __restrict__ gru_Wih,
                       const float* __restrict__ gru_Whh,
                       unsigned short* __restrict__ cur0b,
                       unsigned short* __restrict__ PA, unsigned short* __restrict__ PB,
                       unsigned short* __restrict__ WF)
{
    __shared__ float wsh[F_ * (FA_ + FB_)];   // 9800 floats = 39.2 KB
    const int tid = threadIdx.x;

    if (blockIdx.x >= NPREP) {
        // ---- build_frags part: bf16 B-fragments, 14 F×F matrices, zero-padded ----
        const int i = (blockIdx.x - NPREP) * NT + tid;
        if (i >= FRAG_TOTAL) return;
        const int lane = i & 63;
        int rest = i >> 6;
        const int ks = rest % KSTEPS; rest /= KSTEPS;
        const int t  = rest % NTL;
        const int m  = rest / NTL;
        const int n  = t * 16 + (lane & 15);
        const int k0 = ks * 32 + ((lane >> 4) << 3);
        const int r = m / 7, tt = m - r * 7;
        const float* src;
        if (tt == 0)      src = attend_W + (size_t)r * MSZ;
        else if (tt <= 3) src = gru_Wih + ((size_t)r * 3 + (tt - 1)) * MSZ;
        else              src = gru_Whh + ((size_t)r * 3 + (tt - 4)) * MSZ;
        unsigned short o[8];
        #pragma unroll
        for (int j = 0; j < 8; ++j) {
            const int k = k0 + j;
            const float v = (n < F_ && k < F_) ? src[(size_t)n * F_ + k] : 0.0f;
            o[j] = f2b(v);
        }
        uint4 w;
        w.x = (unsigned int)o[0] | ((unsigned int)o[1] << 16);
        w.y = (unsigned int)o[2] | ((unsigned int)o[3] << 16);
        w.z = (unsigned int)o[4] | ((unsigned int)o[5] << 16);
        w.w = (unsigned int)o[6] | ((unsigned int)o[7] << 16);
        ((uint4*)WF)[i] = w;
        return;
    }

    // ---- prep part: weight-stationary; lane owns column f, weights in regs ----
    const int node0 = blockIdx.x * PN2;
    const int f     = tid;
    const bool valid = (f < F_);
    const int fc    = valid ? f : 0;

    float wa[FA_];
    float wn[FA_ + FB_];

    for (int i = tid; i < F_ * FA_; i += NT) wsh[i] = atom_W[i];
    __syncthreads();
    #pragma unroll
    for (int k = 0; k < FA_; ++k) wa[k] = wsh[fc * FA_ + k];
    __syncthreads();
    for (int i = tid; i < F_ * (FA_ + FB_); i += NT) wsh[i] = nbr_W[i];
    __syncthreads();
    #pragma unroll
    for (int k = 0; k < FA_ + FB_; ++k) wn[k] = wsh[fc * (FA_ + FB_) + k];
    __syncthreads();   // wn copies done -> wsh is free

    // stage the node input rows into wsh (contiguous -> fully coalesced);
    // the node loop then reads LDS broadcasts instead of a serial chain of
    // ~200cy wave-uniform global loads.
    {
        const float* asrc = atom_list + (size_t)node0 * FA_;
        for (int i = tid; i < PN2 * FA_; i += NT) wsh[i] = asrc[i];
        const float* bsrc = bond_list + (size_t)node0 * FB_;
        for (int i = tid; i < PN2 * FB_; i += NT) wsh[PN2 * FA_ + i] = bsrc[i];
    }
    __syncthreads();

    const float ab = atom_b[fc];

    for (int n = 0; n < PN2; ++n) {
        const float* __restrict__ ar = &wsh[n * FA_];
        const float* __restrict__ br = &wsh[PN2 * FA_ + n * FB_];
        float accA = ab, accPA = 0.0f, accPB = 0.0f;
        #pragma unroll
        for (int k = 0; k < FA_; ++k) {
            const float a = ar[k];          // LDS broadcast (same addr all lanes)
            accA  += a * wa[k];
            accPA += a * wn[k];
        }
        #pragma unroll
        for (int k = 0; k < FB_; ++k) accPB += br[k] * wn[FA_ + k];
        if (valid) {
            const size_t o = (size_t)(node0 + n) * F_ + f;
            cur0b[o] = f2b(lrelu(accA));
            PA[o]    = f2b(accPA);
            PB[o]    = f2b(accPB);
        }
    }
}

// ===== mode-0 pair-score table: s2p[q] = alW2 · lrelu(PA[nidx]+PB[bidx]+nbr_b) =====
#define PPB 32   // pairs per block, 8 lanes each
__global__ __launch_bounds__(NT)
void pair_score_kernel(const int* __restrict__ atom_degree,
                       const int* __restrict__ bond_degree,
                       const unsigned short* __restrict__ PA,
                       const unsigned short* __restrict__ PB,
                       const float* __restrict__ alW2, const float* __restrict__ nbr_b,
                       float* __restrict__ s2p)
{
    __shared__ float w_s[F_], b_s[F_];
    const int tid = threadIdx.x;
    if (tid < F_) { w_s[tid] = alW2[tid]; b_s[tid] = nbr_b[tid]; }
    // XCD-aligned swizzle: molecule m -> XCD m%8 (matches round_kernel)
    const int xcd = blockIdx.x & 7;
    const int j   = blockIdx.x >> 3;            // 0..767
    const int mol = (j / 24) * 8 + xcd;         // 24 blocks per molecule
    const int q0  = mol * (L_ * D_) + (j % 24) * PPB;
    const int q   = q0 + (tid >> 3);
    const int sub = tid & 7;
    const int nidx = atom_degree[q] & LMASK;
    const int bidx = bond_degree[q] & LMASK;
    const int bL   = mol * L_;
    const unsigned short* pa = PA + (size_t)(bL + nidx) * F_;
    const unsigned short* pb = PB + (size_t)(bL + bidx) * F_;
    __syncthreads();
    float s = 0.0f;
    for (int kk = sub; kk < KC8; kk += 8) {
        const sh8 pa8 = *(const sh8*)(pa + kk * 8);
        const sh8 pb8 = *(const sh8*)(pb + kk * 8);
        #pragma unroll
        for (int e = 0; e < 8; ++e)
            s += lrelu(b2f((unsigned short)pa8[e]) + b2f((unsigned short)pb8[e])
                       + b_s[kk * 8 + e]) * w_s[kk * 8 + e];
    }
    s += __shfl_xor(s, 1, 8); s += __shfl_xor(s, 2, 8); s += __shfl_xor(s, 4, 8);
    if (sub == 0) s2p[q] = s;
}

// ===================== round kernel (MFMA E/F, tile-sequential) =====================
// r12 structure, all-bf16 state: fp32 cur dropped everywhere (absmax has been
// pinned at 2^-8 by the bf16 MFMA path since r0 — the fp32 plumbing was
// precision-overkill). s1 and the GRU-epilogue cv read the bf16 shadow;
// mode 0 writes ONLY the bf16 shadow; mode 1 writes the fp32 output.
__global__ __launch_bounds__(NT, 4)
void round_kernel(
    const int*   __restrict__ atom_degree,
    const int*   __restrict__ bond_degree,
    const float* __restrict__ align_W,       // [2F] this round (first half used)
    const float* __restrict__ align_b,       // [1]
    const unsigned short* __restrict__ WF,   // 7 fragment matrices this round
    const float* __restrict__ attend_b,
    const float* __restrict__ gru_bih,
    const float* __restrict__ gru_bhh,
    const float* __restrict__ nbr_b,         // mode0
    const unsigned short* __restrict__ PAb,  // mode0, bf16
    const unsigned short* __restrict__ PBb,  // mode0, bf16
    const float* __restrict__ s2_tab,        // mode0: per-pair table; mode1: per-node
    const unsigned short* __restrict__ cur_inb, // [B,L,F] bf16 (s1, A, D, cv)
    float*       __restrict__ dst,           // mode1: fp32 output
    unsigned short* __restrict__ dstb,       // mode0: bf16 shadow out
    const float* __restrict__ alW2_next,     // mode0: round-1 alW2 for fused s2
    float*       __restrict__ s2_next,       // mode0: fused s2 output [NNODES]
    int mode)
{
    // XCD swizzle: all 8 tiles of a molecule share (blockIdx % 8) -> same XCD L2
    const int bid   = blockIdx.x;
    const int mol   = ((bid >> 6) << 3) | (bid & 7);
    const int tile  = (bid >> 3) & 7;
    const int node0 = mol * L_ + tile * NTILE;
    const int bL    = mol * L_;
    const int tid   = threadIdx.x;
    const int lane  = tid & 63;
    const int wave  = tid >> 6;

    __shared__ __align__(16) unsigned short curb  [NTILE][KPP];  // bf16 A-operands
    __shared__ __align__(16) unsigned short mixedb[NTILE][KPP];
    __shared__ __align__(16) unsigned short ctxb  [NTILE][KPP];
    __shared__ __align__(16) float nbrb_s[F_];
    __shared__ float sc_s [NQ];
    __shared__ float asum_s[NTILE];
    __shared__ float s2acc[NTILE];
    __shared__ int   nidx_s[NQ];
    __shared__ int   bidx_s[NQ];

    // zero K-pads [F_, KP) (MFMA reads them; pad x Wpad = 0 required)
    for (int idx = tid; idx < NTILE * (KP - F_); idx += NT) {
        const int n = idx / (KP - F_), k = F_ + idx % (KP - F_);
        curb[n][k] = 0; mixedb[n][k] = 0; ctxb[n][k] = 0;
    }
    if (tid < NTILE) s2acc[tid] = 0.0f;
    if (mode == 0 && tid < F_) nbrb_s[tid] = nbr_b[tid];

    // Phase A: own cur rows -> bf16 LDS (pure 16B copy from bf16 shadow)
    for (int idx = tid; idx < NTILE * KC8; idx += NT) {
        const int n = idx / KC8, kk = idx - n * KC8;
        *(uint4*)&curb[n][kk * 8] =
            *(const uint4*)(cur_inb + (size_t)(node0 + n) * F_ + kk * 8);
    }

    // Fused s1 + align-score + softmax (16 lanes per node, no intermediate barriers)
    {
        const int n = tid >> 4, sub = tid & 15;
        const unsigned short* crow = cur_inb + (size_t)(node0 + n) * F_;
        float s1 = 0.0f;
        for (int f = sub; f < F_; f += 16) s1 += b2f(crow[f]) * align_W[f];
        s1 += __shfl_xor(s1, 1, 16); s1 += __shfl_xor(s1, 2, 16);
        s1 += __shfl_xor(s1, 4, 16); s1 += __shfl_xor(s1, 8, 16);
        // lanes 0..5 score their pair; 6..15 hold -inf filler
        float sc = -3.0e38f;
        int nidx = 0, bidx = 0;
        if (sub < D_) {
            nidx = atom_degree[(node0 + n) * D_ + sub] & LMASK;
            if (mode == 0) bidx = bond_degree[(node0 + n) * D_ + sub] & LMASK;
            const float s2v = (mode == 0)
                ? s2_tab[(size_t)(node0 + n) * D_ + sub]
                : s2_tab[bL + nidx];
            sc = lrelu(s1 + s2v + align_b[0]);
            if (nidx == PAD_) sc += -9.0e8f;
        }
        // width-8 softmax (lanes 6,7: exp(-inf)=0 contribute nothing)
        float mx = sc;
        mx = fmaxf(mx, __shfl_xor(mx, 1, 8));
        mx = fmaxf(mx, __shfl_xor(mx, 2, 8));
        mx = fmaxf(mx, __shfl_xor(mx, 4, 8));
        const float ex = __expf(sc - mx);
        float ssum = ex;
        ssum += __shfl_xor(ssum, 1, 8);
        ssum += __shfl_xor(ssum, 2, 8);
        ssum += __shfl_xor(ssum, 4, 8);
        const float inv = 1.0f / ssum;
        const float aw = (sub < D_ && nidx != PAD_) ? ex * inv : 0.0f;
        if (sub < D_) {
            sc_s[n * D_ + sub]   = aw;
            nidx_s[n * D_ + sub] = nidx;
            if (mode == 0) bidx_s[n * D_ + sub] = bidx;
        }
        float as = aw;
        as += __shfl_xor(as, 1, 8);
        as += __shfl_xor(as, 2, 8);
        as += __shfl_xor(as, 4, 8);
        if (sub == 0) asum_s[n] = as;
    }
    __syncthreads();

    // Phase D: mixed[n] = sum_j attn_j * nbr_feat_j -> bf16 LDS (bf16 gathers)
    for (int idx = tid; idx < NTILE * KC8; idx += NT) {
        const int n = idx / KC8, kk = idx - n * KC8;
        const int c0 = kk * 8;
        float m[8];
        #pragma unroll
        for (int e = 0; e < 8; ++e) m[e] = 0.0f;
        if (mode == 0) {
            #pragma unroll
            for (int j = 0; j < D_; ++j) {
                const float a = sc_s[n * D_ + j];
                const sh8 pa8 = *(const sh8*)(PAb + (size_t)(bL + nidx_s[n*D_+j]) * F_ + c0);
                const sh8 pb8 = *(const sh8*)(PBb + (size_t)(bL + bidx_s[n*D_+j]) * F_ + c0);
                #pragma unroll
                for (int e = 0; e < 8; ++e)
                    m[e] += a * lrelu(b2f((unsigned short)pa8[e])
                                    + b2f((unsigned short)pb8[e]) + nbrb_s[c0 + e]);
            }
        } else {
            #pragma unroll
            for (int j = 0; j < D_; ++j) {
                const float a = sc_s[n * D_ + j];
                const sh8 v8 = *(const sh8*)(cur_inb + (size_t)(bL + nidx_s[n*D_+j]) * F_ + c0);
                #pragma unroll
                for (int e = 0; e < 8; ++e)
                    m[e] += a * b2f((unsigned short)v8[e]);
            }
        }
        uint4 w;
        w.x = (unsigned int)f2b(m[0]) | ((unsigned int)f2b(m[1]) << 16);
        w.y = (unsigned int)f2b(m[2]) | ((unsigned int)f2b(m[3]) << 16);
        w.z = (unsigned int)f2b(m[4]) | ((unsigned int)f2b(m[5]) << 16);
        w.w = (unsigned int)f2b(m[6]) | ((unsigned int)f2b(m[7]) << 16);
        *(uint4*)&mixedb[n][c0] = w;
    }
    __syncthreads();

    // ---- Phase E (MFMA, tile-sequential): ctx = elu(attend_W @ mixed + asum*b) ----
    for (int t = wave; t < NTL; t += 4) {
        f32x4 acc = {0.f, 0.f, 0.f, 0.f};
        #pragma unroll
        for (int ks = 0; ks < KSTEPS; ++ks)
            acc = __builtin_amdgcn_mfma_f32_16x16x32_bf16(
                AFRAG(mixedb, ks), bfrag(WF, 0, t, ks, lane), acc, 0, 0, 0);
        const int f = t * 16 + (lane & 15);
        if (f < F_) {
            const float bb = attend_b[f];
            #pragma unroll
            for (int rg = 0; rg < 4; ++rg) {
                const int node = ((lane >> 4) << 2) + rg;
                float c = acc[rg] + asum_s[node] * bb;
                c = (c > 0.0f) ? c : (__expf(c) - 1.0f);
                ctxb[node][f] = f2b(c);
            }
        }
    }
    __syncthreads();

    // ---- Phase F (MFMA, tile-sequential): GRU gates (+ fused next-round s2) ----
    float s2part[4] = {0.f, 0.f, 0.f, 0.f};
    for (int t = wave; t < NTL; t += 4) {
        f32x4 ar = {0.f,0.f,0.f,0.f}, az = {0.f,0.f,0.f,0.f};
        f32x4 ani = {0.f,0.f,0.f,0.f}, anh = {0.f,0.f,0.f,0.f};
        #pragma unroll
        for (int ks = 0; ks < KSTEPS; ++ks) {
            const sh8 ac = AFRAG(ctxb, ks);
            const sh8 ah = AFRAG(curb, ks);
            ar  = __builtin_amdgcn_mfma_f32_16x16x32_bf16(ac, bfrag(WF,1,t,ks,lane), ar, 0,0,0);
            ar  = __builtin_amdgcn_mfma_f32_16x16x32_bf16(ah, bfrag(WF,4,t,ks,lane), ar, 0,0,0);
            az  = __builtin_amdgcn_mfma_f32_16x16x32_bf16(ac, bfrag(WF,2,t,ks,lane), az, 0,0,0);
            az  = __builtin_amdgcn_mfma_f32_16x16x32_bf16(ah, bfrag(WF,5,t,ks,lane), az, 0,0,0);
            ani = __builtin_amdgcn_mfma_f32_16x16x32_bf16(ac, bfrag(WF,3,t,ks,lane), ani, 0,0,0);
            anh = __builtin_amdgcn_mfma_f32_16x16x32_bf16(ah, bfrag(WF,6,t,ks,lane), anh, 0,0,0);
        }
        const int f = t * 16 + (lane & 15);
        if (f < F_) {
            const float bir = gru_bih[f],        bhr = gru_bhh[f];
            const float biz = gru_bih[F_ + f],   bhz = gru_bhh[F_ + f];
            const float bin = gru_bih[2*F_ + f], bhn = gru_bhh[2*F_ + f];
            const float w2 = (mode == 0) ? alW2_next[f] : 0.0f;
            #pragma unroll
            for (int rg = 0; rg < 4; ++rg) {
                const int node = ((lane >> 4) << 2) + rg;
                const float r  = sigm(ar[rg] + bir + bhr);
                const float z  = sigm(az[rg] + biz + bhz);
                const float nn = fast_tanh(ani[rg] + bin + r * (anh[rg] + bhn));
                const size_t o = (size_t)(node0 + node) * F_ + f;
                const float cv = b2f(cur_inb[o]);
                const float h  = fmaxf((1.0f - z) * nn + z * cv, 0.0f);
                if (mode == 0) { dstb[o] = f2b(h); s2part[rg] += h * w2; }
                else           { dst[o] = h; }
            }
        }
    }

    if (mode == 0) {
        // reduce s2part across the 16 lanes of each quarter-wave, then LDS-accumulate
        #pragma unroll
        for (int rg = 0; rg < 4; ++rg) {
            float v = s2part[rg];
            v += __shfl_xor(v, 1, 16); v += __shfl_xor(v, 2, 16);
            v += __shfl_xor(v, 4, 16); v += __shfl_xor(v, 8, 16);
            if ((lane & 15) == 0) atomicAdd(&s2acc[((lane >> 4) << 2) + rg], v);
        }
        __syncthreads();
        if (tid < NTILE) s2_next[node0 + tid] = s2acc[tid];
    }
}

extern "C" __attribute__((visibility("default")))
void kernel_launch(void* const* d_in, const int* in_sizes, int n_in,
                   void* d_out, int out_size, void* d_ws, size_t ws_size,
                   hipStream_t stream) {
    const float* atom_list = (const float*)d_in[0];
    const float* bond_list = (const float*)d_in[1];
    const int*   atom_deg  = (const int*)d_in[2];
    const int*   bond_deg  = (const int*)d_in[3];
    const float* atom_W    = (const float*)d_in[4];
    const float* atom_b    = (const float*)d_in[5];
    const float* nbr_W     = (const float*)d_in[6];
    const float* nbr_b     = (const float*)d_in[7];
    const float* align_W   = (const float*)d_in[8];
    const float* align_b   = (const float*)d_in[9];
    const float* attend_W  = (const float*)d_in[10];
    const float* attend_b  = (const float*)d_in[11];
    const float* gru_Wih   = (const float*)d_in[12];
    const float* gru_Whh   = (const float*)d_in[13];
    const float* gru_bih   = (const float*)d_in[14];
    const float* gru_bhh   = (const float*)d_in[15];

    float* ws   = (float*)d_ws;
    float* s2b  = ws;                       // NNODES fp32
    float* s2p  = s2b + NNODES;             // NPAIRS fp32
    unsigned short* cur0b = (unsigned short*)(s2p + NPAIRS);          // NF bf16
    unsigned short* cur1b = cur0b + (size_t)NF;                        // NF bf16
    unsigned short* PAb   = cur1b + (size_t)NF;                        // NF bf16
    unsigned short* PBb   = PAb   + (size_t)NF;                        // NF bf16
    unsigned short* WF    = PBb   + (size_t)NF;                        // 1.3 MB frags
    float* out  = (float*)d_out;

    prep_frags_kernel<<<dim3(NPREP + NBF), dim3(NT), 0, stream>>>(
        atom_list, bond_list, atom_W, atom_b, nbr_W,
        attend_W, gru_Wih, gru_Whh,
        cur0b, PAb, PBb, WF);

    pair_score_kernel<<<dim3(NPAIRS / PPB), dim3(NT), 0, stream>>>(
        atom_deg, bond_deg, PAb, PBb, align_W + F_, nbr_b, s2p);

    const dim3 grid(NNODES / NTILE);
    const size_t rframe = (size_t)7 * NTL * KSTEPS * 64 * 8;  // shorts per round

    round_kernel<<<grid, dim3(NT), 0, stream>>>(
        atom_deg, bond_deg, align_W, align_b,
        WF, attend_b, gru_bih, gru_bhh,
        nbr_b, PAb, PBb, /*s2_tab*/s2p, cur0b, /*dst*/nullptr, /*dstb*/cur1b,
        /*alW2_next*/align_W + 2 * F_ + F_, /*s2_next*/s2b, 0);

    round_kernel<<<grid, dim3(NT), 0, stream>>>(
        atom_deg, bond_deg, align_W + 2 * F_, align_b + 1,
        WF + rframe, attend_b + F_, gru_bih + 3 * F_, gru_bhh + 3 * F_,
        nbr_b, PAb, PBb, s2b, cur1b, /*dst*/out, /*dstb*/nullptr,
        /*alW2_next*/nullptr, /*s2_next*/nullptr, 1);
}